// Round 10
// baseline (146.325 us; speedup 1.0000x reference)
//
#include <hip/hip_runtime.h>
#include <hip/hip_fp16.h>

#define NN   50000
#define FIN  256
#define C1   64        // HEADS*HID
#define NH   8
#define NC   16
#define NE   1600000
#define NTOT (NE + NN)

#define CH   256                        // pass-1 chunks
#define EPC  ((NTOT + CH - 1) / CH)     // 6446 edges per chunk
#define NCB  196                        // coarse buckets: dst>>8
#define GB1  ((NN + 63) / 64)           // 782 gemm1 blocks

typedef _Float16 half8 __attribute__((ext_vector_type(8)));
typedef _Float16 half4 __attribute__((ext_vector_type(4)));
typedef float f32x4 __attribute__((ext_vector_type(4)));

// ---- workspace layout (float-indexed), 36.0 MB ----
// LIVE RANGES (floats):
//   h1h  [0, 1.6M)        fp16 h1, NN*64 halves = 1.6M floats   (g1rh -> agg1)
//   g1h  [1.6M, 3.2M)     fp16 g1, NN*64 halves = 1.6M floats   (agg1 -> gemm2)
//   stage[3.2M, 4.85M)    int[NTOT], sort staging ONLY          (rscatter -> fsort)
//   h2h  [3.2M, 3.6M)     fp16 h2, NN*16 halves = 400K floats   (gemm2 -> agg2; after stage dead)
//   als2 [3.6M, 3.65M)  ald2 [3.65M, 3.7M)                      (gemm2 -> agg2)
//   als1 [6.4M, 6.8M)   ald1 [6.8M, 7.2M)                       (g1rh -> agg1)
//   sort metadata >= 7.2M
#define OFF_H1H   0
#define OFF_G1H   1600000
#define OFF_STAGE 3200000
#define OFF_H2H   3200000    // reuses stage region (stage dead after k_fsort)
#define OFF_ALS2  3600000
#define OFF_ALD2  3650000
#define OFF_ALS1  6400000
#define OFF_ALD1  6800000
#define OFF_HM    7200000    // int H[CH*NCB]
#define OFF_BASEK 7251000    // int basek[NCB*CH]
#define OFF_BBASE 7302000    // int bbase[NCB+1] (+btot scratch behind)
#define OFF_OFFS  7302400    // int offs[NN+1]
#define OFF_SRC   7352500    // int ssrc[NTOT]
// end = 9,002,500 floats = 36.0 MB

// ------- K1: [blocks 0..781] h1=x@W1 MFMA (single K-stage, 2 barriers)
//         [blocks 782..1037] rh: per-chunk coarse histogram
__global__ __launch_bounds__(256) void k_g1rh(const float* __restrict__ x,
                                              const float* __restrict__ W1,
                                              const float* __restrict__ as1,
                                              const float* __restrict__ ad1,
                                              __half* __restrict__ h1h,
                                              float* __restrict__ als,
                                              float* __restrict__ ald,
                                              const int* __restrict__ ei,
                                              int* __restrict__ H) {
    __shared__ _Float16 wsT[64][264];   // [col][k]  33.8 KB
    __shared__ _Float16 xs[64][264];    // [row][k]  33.8 KB
    const int tid = threadIdx.x;

    if (blockIdx.x >= GB1) {            // ---- rh branch ----
        __shared__ int lh[NCB];
        int k = blockIdx.x - GB1;
        for (int i = tid; i < NCB; i += 256) lh[i] = 0;
        __syncthreads();
        int e0 = k * EPC, e1 = min(e0 + EPC, NTOT);
        for (int e = e0 + tid; e < e1; e += 256) {
            int d = (e < NE) ? ei[NE + e] : (e - NE);
            atomicAdd(&lh[d >> 8], 1);
        }
        __syncthreads();
        for (int i = tid; i < NCB; i += 256) H[k * NCB + i] = lh[i];
        return;
    }

    // ---- gemm1 branch ----
    const int r0 = blockIdx.x * 64;
    // stage W1 -> wsT[col][k]
    {
        int c = tid & 63, kb = tid >> 6;
        #pragma unroll
        for (int j = 0; j < 8; ++j) {
            int k8 = kb + 4 * j;
            half8 hv;
            #pragma unroll
            for (int u = 0; u < 8; ++u)
                hv[u] = (_Float16)W1[(size_t)(k8 * 8 + u) * C1 + c];
            *(half8*)(&wsT[c][k8 * 8]) = hv;
        }
    }
    // stage x tile -> xs[row][k], full K=256
    {
        int row = tid >> 2, cb = (tid & 3) * 64;
        int grow = r0 + row;
        #pragma unroll
        for (int j = 0; j < 8; ++j) {
            float4 v0 = make_float4(0.f,0.f,0.f,0.f), v1 = v0;
            if (grow < NN) {
                const float4* xp = (const float4*)(&x[(size_t)grow * FIN + cb + j * 8]);
                v0 = xp[0]; v1 = xp[1];
            }
            half8 hv;
            hv[0]=(_Float16)v0.x; hv[1]=(_Float16)v0.y; hv[2]=(_Float16)v0.z; hv[3]=(_Float16)v0.w;
            hv[4]=(_Float16)v1.x; hv[5]=(_Float16)v1.y; hv[6]=(_Float16)v1.z; hv[7]=(_Float16)v1.w;
            *(half8*)(&xs[row][cb + j * 8]) = hv;
        }
    }
    __syncthreads();

    const int lane = tid & 63;
    const int wv   = tid >> 6;
    const int colb = lane & 15;
    const int rgrp = lane >> 4;
    f32x4 acc[4] = {};
    #pragma unroll
    for (int s = 0; s < 8; ++s) {
        half8 a = *(half8*)(&xs[wv * 16 + colb][s * 32 + rgrp * 8]);
        #pragma unroll
        for (int ct = 0; ct < 4; ++ct) {
            half8 b = *(half8*)(&wsT[ct * 16 + colb][s * 32 + rgrp * 8]);
            acc[ct] = __builtin_amdgcn_mfma_f32_16x16x32_f16(a, b, acc[ct], 0, 0, 0);
        }
    }

    float a_s[4], a_d[4];
    #pragma unroll
    for (int ct = 0; ct < 4; ++ct) { a_s[ct] = as1[ct * 16 + colb]; a_d[ct] = ad1[ct * 16 + colb]; }
    #pragma unroll
    for (int j = 0; j < 4; ++j) {
        int row = r0 + wv * 16 + rgrp * 4 + j;
        bool rv = row < NN;
        #pragma unroll
        for (int ct = 0; ct < 4; ++ct) {
            if (rv) h1h[(size_t)row * C1 + ct * 16 + colb] = __float2half(acc[ct][j]);
            float p = acc[ct][j] * a_s[ct];
            p += __shfl_xor(p, 1); p += __shfl_xor(p, 2); p += __shfl_xor(p, 4);
            float q = acc[ct][j] * a_d[ct];
            q += __shfl_xor(q, 1); q += __shfl_xor(q, 2); q += __shfl_xor(q, 4);
            if (rv && (lane & 7) == 0) {
                int head = ct * 2 + (colb >> 3);
                als[row * NH + head] = p;
                ald[row * NH + head] = q;
            }
        }
    }
}

// ======== deterministic 2-pass counting sort (no global atomics) =========
__global__ __launch_bounds__(256) void k_rsA(const int* __restrict__ H,
                                             int* __restrict__ basek,
                                             int* __restrict__ btot) {
    __shared__ int sc[CH];
    int b = blockIdx.x, t = threadIdx.x;
    int v = H[t * NCB + b];
    sc[t] = v;
    __syncthreads();
    for (int s = 1; s < CH; s <<= 1) {
        int u = (t >= s) ? sc[t - s] : 0;
        __syncthreads();
        sc[t] += u;
        __syncthreads();
    }
    basek[b * CH + t] = sc[t] - v;
    if (t == CH - 1) btot[b] = sc[t];
}

__global__ __launch_bounds__(64) void k_rsB(int* __restrict__ btot,
                                            int* __restrict__ bbase,
                                            int* __restrict__ offs) {
    if (threadIdx.x == 0) {
        int run = 0;
        for (int b = 0; b < NCB; ++b) {
            bbase[b] = run;
            run += btot[b];
        }
        bbase[NCB] = run;
        offs[NN] = NTOT;
    }
}

__global__ __launch_bounds__(256) void k_rscatter(const int* __restrict__ ei,
                                                  const int* __restrict__ basek,
                                                  const int* __restrict__ bbase,
                                                  int* __restrict__ stage) {
    __shared__ int lcur[NCB];
    int k = blockIdx.x;
    for (int i = threadIdx.x; i < NCB; i += 256)
        lcur[i] = bbase[i] + basek[i * CH + k];
    __syncthreads();
    int e0 = k * EPC, e1 = min(e0 + EPC, NTOT);
    for (int e = e0 + threadIdx.x; e < e1; e += 256) {
        int s, d;
        if (e < NE) { s = ei[e]; d = ei[NE + e]; }
        else        { s = e - NE; d = s; }
        int pos = atomicAdd(&lcur[d >> 8], 1);
        stage[pos] = (s << 8) | (d & 255);
    }
}

__global__ __launch_bounds__(256) void k_fsort(const int* __restrict__ stage,
                                               const int* __restrict__ bbase,
                                               int* __restrict__ offs,
                                               int* __restrict__ ssrc) {
    __shared__ int lc[256];
    __shared__ int ls[256];
    __shared__ int lcur[256];
    int b = blockIdx.x, t = threadIdx.x;
    int base = bbase[b];
    int n = bbase[b + 1] - base;
    lc[t] = 0;
    __syncthreads();
    const int* sp = &stage[base];
    for (int i = t; i < n; i += 256) atomicAdd(&lc[sp[i] & 255], 1);
    __syncthreads();
    int v = lc[t];
    ls[t] = v;
    __syncthreads();
    for (int s = 1; s < 256; s <<= 1) {
        int u = (t >= s) ? ls[t - s] : 0;
        __syncthreads();
        ls[t] += u;
        __syncthreads();
    }
    int excl = ls[t] - v;
    int d = b * 256 + t;
    if (d < NN) offs[d] = base + excl;
    lcur[t] = base + excl;
    __syncthreads();
    for (int i = t; i < n; i += 256) {
        int u = sp[i];
        int pos = atomicAdd(&lcur[u & 255], 1);
        ssrc[pos] = u >> 8;
    }
}

// ------- K2: layer-1 aggregation (quarter half4 gathers), lean epilogue ----
// wave per dst. lane l: q=l>>4, lc=l&15 gathers channels 4lc..4lc+3 (head lc>>1)
// of edge slots {4i+q}; weight duty: lane computes w for slots l>>3, (l>>3)+8, head l&7.
__global__ __launch_bounds__(256) void k_agg1(const int* __restrict__ offs,
                                              const int* __restrict__ src,
                                              const __half* __restrict__ h1h,
                                              const float* __restrict__ als,
                                              const float* __restrict__ ald,
                                              const float* __restrict__ b1,
                                              _Float16* __restrict__ g1h) {
    int d = blockIdx.x * 4 + (threadIdx.x >> 6);
    if (d >= NN) return;
    const int l  = threadIdx.x & 63;
    const int q  = l >> 4, lc = l & 15;
    const int hg = lc >> 1;
    const int sub = l >> 3, hw = l & 7;
    const int lane_a = (q << 3) | hg;
    const int lane_b = lane_a + 32;
    int beg = offs[d], end = offs[d + 1];
    float aldv = ald[d * NH + hw];
    f32x4 acc = {0.f, 0.f, 0.f, 0.f};
    float den = 0.f;

    for (int r = beg; r < end; r += 16) {
        int e0 = r + sub, e1 = e0 + 8;
        bool v0 = e0 < end, v1 = e1 < end;
        int s0 = src[v0 ? e0 : end - 1];
        int s1 = src[v1 ? e1 : end - 1];
        float lg0 = als[s0 * NH + hw] + aldv;
        float lg1 = als[s1 * NH + hw] + aldv;
        lg0 = lg0 > 0.f ? lg0 : 0.2f * lg0;
        lg1 = lg1 > 0.f ? lg1 : 0.2f * lg1;
        float w0 = v0 ? __expf(lg0) : 0.f;
        float w1 = v1 ? __expf(lg1) : 0.f;
        #pragma unroll
        for (int i = 0; i < 4; ++i) {
            int srcl = (i & 1) ? lane_b : lane_a;
            int sv   = __shfl((i < 2) ? s0 : s1, srcl);
            float wvv= __shfl((i < 2) ? w0 : w1, srcl);
            half4 hv = *(const half4*)(&h1h[(size_t)sv * C1 + 4 * lc]);
            acc[0] += wvv * (float)hv[0];
            acc[1] += wvv * (float)hv[1];
            acc[2] += wvv * (float)hv[2];
            acc[3] += wvv * (float)hv[3];
            den += wvv;
        }
    }
    #pragma unroll
    for (int k = 0; k < 4; ++k) {
        acc[k] += __shfl_xor(acc[k], 16);
        acc[k] += __shfl_xor(acc[k], 32);
    }
    den += __shfl_xor(den, 16);
    den += __shfl_xor(den, 32);
    if (q == 0) {
        half4 gv;
        #pragma unroll
        for (int k = 0; k < 4; ++k) {
            float o = acc[k] / den + b1[4 * lc + k];
            o = o > 0.f ? o : (__expf(o) - 1.f);
            gv[k] = (_Float16)o;
        }
        *(half4*)(&g1h[(size_t)d * C1 + 4 * lc]) = gv;
    }
}

// ---------------- K3: GEMM2 (64->16, fp16 in) + layer-2 logits ----------------
__global__ __launch_bounds__(256) void k_gemm2(const _Float16* __restrict__ g1h,
                                               const float* __restrict__ W2,
                                               const float* __restrict__ as2,
                                               const float* __restrict__ ad2,
                                               _Float16* __restrict__ h2h,
                                               float* __restrict__ als2,
                                               float* __restrict__ ald2) {
    __shared__ float w2s[C1][17];
    __shared__ _Float16 hact[16][C1 + 8];
    int tid = threadIdx.x;
    for (int i = tid; i < C1 * NC; i += 256) w2s[i >> 4][i & 15] = W2[i];
    int ln = tid >> 4, j = tid & 15;
    int n = blockIdx.x * 16 + ln;
    if (n < NN)
        *(half4*)(&hact[ln][j * 4]) = *(const half4*)(&g1h[(size_t)n * C1 + j * 4]);
    __syncthreads();
    if (n >= NN) return;
    float sum = 0.f;
    #pragma unroll
    for (int c = 0; c < C1; ++c) sum += (float)hact[ln][c] * w2s[c][j];
    h2h[(size_t)n * NC + j] = (_Float16)sum;
    float ps = sum * as2[j], pd = sum * ad2[j];
    #pragma unroll
    for (int w = 1; w < 16; w <<= 1) {
        ps += __shfl_xor(ps, w);
        pd += __shfl_xor(pd, w);
    }
    if (j == 0) { als2[n] = ps; ald2[n] = pd; }
}

// ------- K4: layer-2 aggregation (fp16 h2), 16 lanes/dst, 4-edge ILP ------
__global__ __launch_bounds__(256) void k_agg2(const int* __restrict__ offs,
                                              const int* __restrict__ src,
                                              const _Float16* __restrict__ h2h,
                                              const float* __restrict__ als2,
                                              const float* __restrict__ ald2,
                                              const float* __restrict__ b2,
                                              float* __restrict__ out) {
    int d = blockIdx.x * 16 + (threadIdx.x >> 4);
    if (d >= NN) return;
    int c = threadIdx.x & 15;
    int beg = offs[d], end = offs[d + 1];
    float aldv = ald2[d];
    float acc = 0.f, den = 0.f;
    for (int r = beg; r < end; r += 4) {
        int e1 = r + 1, e2 = r + 2, e3 = r + 3;
        bool v1 = e1 < end, v2 = e2 < end, v3 = e3 < end;
        int s0 = src[r];
        int s1 = src[v1 ? e1 : end - 1];
        int s2 = src[v2 ? e2 : end - 1];
        int s3 = src[v3 ? e3 : end - 1];
        float l0 = als2[s0] + aldv;
        float l1 = als2[s1] + aldv;
        float l2 = als2[s2] + aldv;
        float l3 = als2[s3] + aldv;
        l0 = l0 > 0.f ? l0 : 0.2f * l0;
        l1 = l1 > 0.f ? l1 : 0.2f * l1;
        l2 = l2 > 0.f ? l2 : 0.2f * l2;
        l3 = l3 > 0.f ? l3 : 0.2f * l3;
        float w0 = __expf(l0);
        float w1 = v1 ? __expf(l1) : 0.f;
        float w2 = v2 ? __expf(l2) : 0.f;
        float w3 = v3 ? __expf(l3) : 0.f;
        float f0 = (float)h2h[(size_t)s0 * NC + c];
        float f1 = (float)h2h[(size_t)s1 * NC + c];
        float f2 = (float)h2h[(size_t)s2 * NC + c];
        float f3 = (float)h2h[(size_t)s3 * NC + c];
        acc += w0 * f0 + w1 * f1 + w2 * f2 + w3 * f3;
        den += w0 + w1 + w2 + w3;
    }
    float o = acc / den + b2[c];
    float m = o;
    #pragma unroll
    for (int w = 1; w < 16; w <<= 1) m = fmaxf(m, __shfl_xor(m, w));
    float ex = __expf(o - m);
    float sm = ex;
    #pragma unroll
    for (int w = 1; w < 16; w <<= 1) sm += __shfl_xor(sm, w);
    out[(size_t)d * NC + c] = o - m - __logf(sm);
}

extern "C" void kernel_launch(void* const* d_in, const int* in_sizes, int n_in,
                              void* d_out, int out_size, void* d_ws, size_t ws_size,
                              hipStream_t stream) {
    const float* x   = (const float*)d_in[0];
    const int*   ei  = (const int*)  d_in[1];
    const float* W1  = (const float*)d_in[2];
    const float* as1 = (const float*)d_in[3];
    const float* ad1 = (const float*)d_in[4];
    const float* b1  = (const float*)d_in[5];
    const float* W2  = (const float*)d_in[6];
    const float* as2 = (const float*)d_in[7];
    const float* ad2 = (const float*)d_in[8];
    const float* b2  = (const float*)d_in[9];
    float* ws  = (float*)d_ws;
    float* out = (float*)d_out;

    __half*    h1h  = (__half*)(ws + OFF_H1H);
    _Float16*  g1h  = (_Float16*)(ws + OFF_G1H);
    _Float16*  h2h  = (_Float16*)(ws + OFF_H2H);
    float* als1 = ws + OFF_ALS1;
    float* ald1 = ws + OFF_ALD1;
    float* als2 = ws + OFF_ALS2;
    float* ald2 = ws + OFF_ALD2;
    int* H      = (int*)(ws + OFF_HM);
    int* basek  = (int*)(ws + OFF_BASEK);
    int* bbase  = (int*)(ws + OFF_BBASE);
    int* offs   = (int*)(ws + OFF_OFFS);
    int* ssrc   = (int*)(ws + OFF_SRC);
    int* stage  = (int*)(ws + OFF_STAGE);

    k_g1rh    <<<GB1 + CH,       256, 0, stream>>>(x, W1, as1, ad1, h1h, als1, ald1, ei, H);
    k_rsA     <<<NCB,            256, 0, stream>>>(H, basek, bbase + NCB + 2 /*btot*/);
    k_rsB     <<<1,               64, 0, stream>>>(bbase + NCB + 2, bbase, offs);
    k_rscatter<<<CH,             256, 0, stream>>>(ei, basek, bbase, stage);
    k_fsort   <<<NCB,            256, 0, stream>>>(stage, bbase, offs, ssrc);
    k_agg1    <<<(NN + 3) / 4,   256, 0, stream>>>(offs, ssrc, h1h, als1, ald1, b1, g1h);
    k_gemm2   <<<(NN + 15) / 16, 256, 0, stream>>>(g1h, W2, as2, ad2, h2h, als2, ald2);
    k_agg2    <<<(NN + 15) / 16, 256, 0, stream>>>(offs, ssrc, h2h, als2, ald2, b2, out);
}

// Round 11
// 138.046 us; speedup vs baseline: 1.0600x; 1.0600x over previous
//
#include <hip/hip_runtime.h>
#include <hip/hip_fp16.h>

#define NN   50000
#define FIN  256
#define C1   64        // HEADS*HID
#define NH   8
#define NC   16
#define NE   1600000
#define NTOT (NE + NN)

#define CH   256                        // pass-1 chunks
#define EPC  ((NTOT + CH - 1) / CH)     // 6446 edges per chunk
#define NCB  196                        // coarse buckets: dst>>8
#define GB1  ((NN + 63) / 64)           // 782 gemm1 blocks

typedef _Float16 half8 __attribute__((ext_vector_type(8)));
typedef _Float16 half4 __attribute__((ext_vector_type(4)));
typedef float f32x4 __attribute__((ext_vector_type(4)));

// ---- workspace layout (float-indexed), 36.0 MB ----
// LIVE RANGES (floats):
//   h1h  [0, 1.6M)        fp16 h1, NN*64 halves                 (g1rh -> agg1)
//   g1h  [1.6M, 3.2M)     fp16 g1, NN*64 halves                 (agg1 -> gemm2)
//   stage[3.2M, 4.85M)    int[NTOT], sort staging ONLY          (rscatter -> fsort)
//   h2h  [3.2M, 3.6M)     fp16 h2 (reuses stage after fsort)    (gemm2 -> agg2)
//   als2 [3.6M, 3.65M)  ald2 [3.65M, 3.7M)                      (gemm2 -> agg2)
//   als1 [6.4M, 6.8M)   ald1 [6.8M, 7.2M)                       (g1rh -> agg1)
//   sort metadata >= 7.2M
#define OFF_H1H   0
#define OFF_G1H   1600000
#define OFF_STAGE 3200000
#define OFF_H2H   3200000
#define OFF_ALS2  3600000
#define OFF_ALD2  3650000
#define OFF_ALS1  6400000
#define OFF_ALD1  6800000
#define OFF_HM    7200000    // int H[CH*NCB]
#define OFF_BASEK 7251000    // int basek[NCB*CH]
#define OFF_BBASE 7302000    // int bbase[NCB+1] (+btot scratch at +198)
#define OFF_OFFS  7302400    // int offs[NN+1]
#define OFF_SRC   7352500    // int ssrc[NTOT]
// end = 9,002,500 floats = 36.0 MB

// ------- K1: [blocks 0..781] h1=x@W1 MFMA (BK=32 pipelined, 4 blocks/CU)
//         [blocks 782..1037] rh: per-chunk coarse histogram
__global__ __launch_bounds__(256) void k_g1rh(const float* __restrict__ x,
                                              const float* __restrict__ W1,
                                              const float* __restrict__ as1,
                                              const float* __restrict__ ad1,
                                              __half* __restrict__ h1h,
                                              float* __restrict__ als,
                                              float* __restrict__ ald,
                                              const int* __restrict__ ei,
                                              int* __restrict__ H) {
    __shared__ _Float16 wsT[64][264];   // [col][k]  33.8 KB
    __shared__ _Float16 xs[64][40];     // [row][k-chunk 32]  5.1 KB
    __shared__ int lh[NCB];
    const int tid = threadIdx.x;

    if (blockIdx.x >= GB1) {            // ---- rh branch ----
        int k = blockIdx.x - GB1;
        for (int i = tid; i < NCB; i += 256) lh[i] = 0;
        __syncthreads();
        int e0 = k * EPC, e1 = min(e0 + EPC, NTOT);
        for (int e = e0 + tid; e < e1; e += 256) {
            int d = (e < NE) ? ei[NE + e] : (e - NE);
            atomicAdd(&lh[d >> 8], 1);
        }
        __syncthreads();
        for (int i = tid; i < NCB; i += 256) H[k * NCB + i] = lh[i];
        return;
    }

    // ---- gemm1 branch ----
    const int r0 = blockIdx.x * 64;
    // stage W1 -> wsT[col][k], coalesced reads, half8 writes
    {
        int c = tid & 63, kb = tid >> 6;
        #pragma unroll
        for (int j = 0; j < 8; ++j) {
            int k8 = kb + 4 * j;            // 0..31
            half8 hv;
            #pragma unroll
            for (int u = 0; u < 8; ++u)
                hv[u] = (_Float16)W1[(size_t)(k8 * 8 + u) * C1 + c];
            *(half8*)(&wsT[c][k8 * 8]) = hv;
        }
    }

    const int lane = tid & 63;
    const int wv   = tid >> 6;
    const int colb = lane & 15;
    const int rgrp = lane >> 4;
    f32x4 acc[4] = {};
    const int srow = tid >> 2;
    const int sq   = tid & 3;
    for (int k0 = 0; k0 < FIN; k0 += 32) {
        __syncthreads();
        {
            int grow = r0 + srow;
            float4 v0 = make_float4(0.f,0.f,0.f,0.f), v1 = v0;
            if (grow < NN) {
                const float4* xp = (const float4*)(&x[(size_t)grow * FIN + k0 + sq * 8]);
                v0 = xp[0]; v1 = xp[1];
            }
            half8 hv;
            hv[0]=(_Float16)v0.x; hv[1]=(_Float16)v0.y; hv[2]=(_Float16)v0.z; hv[3]=(_Float16)v0.w;
            hv[4]=(_Float16)v1.x; hv[5]=(_Float16)v1.y; hv[6]=(_Float16)v1.z; hv[7]=(_Float16)v1.w;
            *(half8*)(&xs[srow][sq * 8]) = hv;
        }
        __syncthreads();
        half8 a = *(half8*)(&xs[wv * 16 + colb][rgrp * 8]);
        #pragma unroll
        for (int ct = 0; ct < 4; ++ct) {
            half8 b = *(half8*)(&wsT[ct * 16 + colb][k0 + rgrp * 8]);
            acc[ct] = __builtin_amdgcn_mfma_f32_16x16x32_f16(a, b, acc[ct], 0, 0, 0);
        }
    }

    float a_s[4], a_d[4];
    #pragma unroll
    for (int ct = 0; ct < 4; ++ct) { a_s[ct] = as1[ct * 16 + colb]; a_d[ct] = ad1[ct * 16 + colb]; }
    #pragma unroll
    for (int j = 0; j < 4; ++j) {
        int row = r0 + wv * 16 + rgrp * 4 + j;
        bool rv = row < NN;
        #pragma unroll
        for (int ct = 0; ct < 4; ++ct) {
            if (rv) h1h[(size_t)row * C1 + ct * 16 + colb] = __float2half(acc[ct][j]);
            float p = acc[ct][j] * a_s[ct];
            p += __shfl_xor(p, 1); p += __shfl_xor(p, 2); p += __shfl_xor(p, 4);
            float q = acc[ct][j] * a_d[ct];
            q += __shfl_xor(q, 1); q += __shfl_xor(q, 2); q += __shfl_xor(q, 4);
            if (rv && (lane & 7) == 0) {
                int head = ct * 2 + (colb >> 3);
                als[row * NH + head] = p;
                ald[row * NH + head] = q;
            }
        }
    }
}

// ======== deterministic 2-pass counting sort (no global atomics) =========
__global__ __launch_bounds__(256) void k_rsA(const int* __restrict__ H,
                                             int* __restrict__ basek,
                                             int* __restrict__ btot) {
    __shared__ int sc[CH];
    int b = blockIdx.x, t = threadIdx.x;
    int v = H[t * NCB + b];
    sc[t] = v;
    __syncthreads();
    for (int s = 1; s < CH; s <<= 1) {
        int u = (t >= s) ? sc[t - s] : 0;
        __syncthreads();
        sc[t] += u;
        __syncthreads();
    }
    basek[b * CH + t] = sc[t] - v;
    if (t == CH - 1) btot[b] = sc[t];
}

// parallel exclusive scan of 196 bucket totals (one block)
__global__ __launch_bounds__(256) void k_rsB(const int* __restrict__ btot,
                                             int* __restrict__ bbase,
                                             int* __restrict__ offs) {
    __shared__ int sc[256];
    int t = threadIdx.x;
    int v = (t < NCB) ? btot[t] : 0;
    sc[t] = v;
    __syncthreads();
    for (int s = 1; s < 256; s <<= 1) {
        int u = (t >= s) ? sc[t - s] : 0;
        __syncthreads();
        sc[t] += u;
        __syncthreads();
    }
    if (t < NCB) bbase[t] = sc[t] - v;
    if (t == NCB - 1) bbase[NCB] = sc[t];
    if (t == 0) offs[NN] = NTOT;
}

__global__ __launch_bounds__(256) void k_rscatter(const int* __restrict__ ei,
                                                  const int* __restrict__ basek,
                                                  const int* __restrict__ bbase,
                                                  int* __restrict__ stage) {
    __shared__ int lcur[NCB];
    int k = blockIdx.x;
    for (int i = threadIdx.x; i < NCB; i += 256)
        lcur[i] = bbase[i] + basek[i * CH + k];
    __syncthreads();
    int e0 = k * EPC, e1 = min(e0 + EPC, NTOT);
    for (int e = e0 + threadIdx.x; e < e1; e += 256) {
        int s, d;
        if (e < NE) { s = ei[e]; d = ei[NE + e]; }
        else        { s = e - NE; d = s; }
        int pos = atomicAdd(&lcur[d >> 8], 1);
        stage[pos] = (s << 8) | (d & 255);
    }
}

__global__ __launch_bounds__(256) void k_fsort(const int* __restrict__ stage,
                                               const int* __restrict__ bbase,
                                               int* __restrict__ offs,
                                               int* __restrict__ ssrc) {
    __shared__ int lc[256];
    __shared__ int ls[256];
    __shared__ int lcur[256];
    int b = blockIdx.x, t = threadIdx.x;
    int base = bbase[b];
    int n = bbase[b + 1] - base;
    lc[t] = 0;
    __syncthreads();
    const int* sp = &stage[base];
    for (int i = t; i < n; i += 256) atomicAdd(&lc[sp[i] & 255], 1);
    __syncthreads();
    int v = lc[t];
    ls[t] = v;
    __syncthreads();
    for (int s = 1; s < 256; s <<= 1) {
        int u = (t >= s) ? ls[t - s] : 0;
        __syncthreads();
        ls[t] += u;
        __syncthreads();
    }
    int excl = ls[t] - v;
    int d = b * 256 + t;
    if (d < NN) offs[d] = base + excl;
    lcur[t] = base + excl;
    __syncthreads();
    for (int i = t; i < n; i += 256) {
        int u = sp[i];
        int pos = atomicAdd(&lcur[u & 255], 1);
        ssrc[pos] = u >> 8;
    }
}

// ------- K2: layer-1 aggregation (quarter half4 gathers), lean epilogue ----
__global__ __launch_bounds__(256) void k_agg1(const int* __restrict__ offs,
                                              const int* __restrict__ src,
                                              const __half* __restrict__ h1h,
                                              const float* __restrict__ als,
                                              const float* __restrict__ ald,
                                              const float* __restrict__ b1,
                                              _Float16* __restrict__ g1h) {
    int d = blockIdx.x * 4 + (threadIdx.x >> 6);
    if (d >= NN) return;
    const int l  = threadIdx.x & 63;
    const int q  = l >> 4, lc = l & 15;
    const int hg = lc >> 1;
    const int sub = l >> 3, hw = l & 7;
    const int lane_a = (q << 3) | hg;
    const int lane_b = lane_a + 32;
    int beg = offs[d], end = offs[d + 1];
    float aldv = ald[d * NH + hw];
    f32x4 acc = {0.f, 0.f, 0.f, 0.f};
    float den = 0.f;

    for (int r = beg; r < end; r += 16) {
        int e0 = r + sub, e1 = e0 + 8;
        bool v0 = e0 < end, v1 = e1 < end;
        int s0 = src[v0 ? e0 : end - 1];
        int s1 = src[v1 ? e1 : end - 1];
        float lg0 = als[s0 * NH + hw] + aldv;
        float lg1 = als[s1 * NH + hw] + aldv;
        lg0 = lg0 > 0.f ? lg0 : 0.2f * lg0;
        lg1 = lg1 > 0.f ? lg1 : 0.2f * lg1;
        float w0 = v0 ? __expf(lg0) : 0.f;
        float w1 = v1 ? __expf(lg1) : 0.f;
        #pragma unroll
        for (int i = 0; i < 4; ++i) {
            int srcl = (i & 1) ? lane_b : lane_a;
            int sv   = __shfl((i < 2) ? s0 : s1, srcl);
            float wvv= __shfl((i < 2) ? w0 : w1, srcl);
            half4 hv = *(const half4*)(&h1h[(size_t)sv * C1 + 4 * lc]);
            acc[0] += wvv * (float)hv[0];
            acc[1] += wvv * (float)hv[1];
            acc[2] += wvv * (float)hv[2];
            acc[3] += wvv * (float)hv[3];
            den += wvv;
        }
    }
    #pragma unroll
    for (int k = 0; k < 4; ++k) {
        acc[k] += __shfl_xor(acc[k], 16);
        acc[k] += __shfl_xor(acc[k], 32);
    }
    den += __shfl_xor(den, 16);
    den += __shfl_xor(den, 32);
    if (q == 0) {
        half4 gv;
        #pragma unroll
        for (int k = 0; k < 4; ++k) {
            float o = acc[k] / den + b1[4 * lc + k];
            o = o > 0.f ? o : (__expf(o) - 1.f);
            gv[k] = (_Float16)o;
        }
        *(half4*)(&g1h[(size_t)d * C1 + 4 * lc]) = gv;
    }
}

// ---------------- K3: GEMM2 (64->16, fp16 in) + layer-2 logits ----------------
__global__ __launch_bounds__(256) void k_gemm2(const _Float16* __restrict__ g1h,
                                               const float* __restrict__ W2,
                                               const float* __restrict__ as2,
                                               const float* __restrict__ ad2,
                                               _Float16* __restrict__ h2h,
                                               float* __restrict__ als2,
                                               float* __restrict__ ald2) {
    __shared__ float w2s[C1][17];
    __shared__ _Float16 hact[16][C1 + 8];
    int tid = threadIdx.x;
    for (int i = tid; i < C1 * NC; i += 256) w2s[i >> 4][i & 15] = W2[i];
    int ln = tid >> 4, j = tid & 15;
    int n = blockIdx.x * 16 + ln;
    if (n < NN)
        *(half4*)(&hact[ln][j * 4]) = *(const half4*)(&g1h[(size_t)n * C1 + j * 4]);
    __syncthreads();
    if (n >= NN) return;
    float sum = 0.f;
    #pragma unroll
    for (int c = 0; c < C1; ++c) sum += (float)hact[ln][c] * w2s[c][j];
    h2h[(size_t)n * NC + j] = (_Float16)sum;
    float ps = sum * as2[j], pd = sum * ad2[j];
    #pragma unroll
    for (int w = 1; w < 16; w <<= 1) {
        ps += __shfl_xor(ps, w);
        pd += __shfl_xor(pd, w);
    }
    if (j == 0) { als2[n] = ps; ald2[n] = pd; }
}

// ------- K4: layer-2 aggregation (fp16 h2), 16 lanes/dst, 4-edge ILP ------
__global__ __launch_bounds__(256) void k_agg2(const int* __restrict__ offs,
                                              const int* __restrict__ src,
                                              const _Float16* __restrict__ h2h,
                                              const float* __restrict__ als2,
                                              const float* __restrict__ ald2,
                                              const float* __restrict__ b2,
                                              float* __restrict__ out) {
    int d = blockIdx.x * 16 + (threadIdx.x >> 4);
    if (d >= NN) return;
    int c = threadIdx.x & 15;
    int beg = offs[d], end = offs[d + 1];
    float aldv = ald2[d];
    float acc = 0.f, den = 0.f;
    for (int r = beg; r < end; r += 4) {
        int e1 = r + 1, e2 = r + 2, e3 = r + 3;
        bool v1 = e1 < end, v2 = e2 < end, v3 = e3 < end;
        int s0 = src[r];
        int s1 = src[v1 ? e1 : end - 1];
        int s2 = src[v2 ? e2 : end - 1];
        int s3 = src[v3 ? e3 : end - 1];
        float l0 = als2[s0] + aldv;
        float l1 = als2[s1] + aldv;
        float l2 = als2[s2] + aldv;
        float l3 = als2[s3] + aldv;
        l0 = l0 > 0.f ? l0 : 0.2f * l0;
        l1 = l1 > 0.f ? l1 : 0.2f * l1;
        l2 = l2 > 0.f ? l2 : 0.2f * l2;
        l3 = l3 > 0.f ? l3 : 0.2f * l3;
        float w0 = __expf(l0);
        float w1 = v1 ? __expf(l1) : 0.f;
        float w2 = v2 ? __expf(l2) : 0.f;
        float w3 = v3 ? __expf(l3) : 0.f;
        float f0 = (float)h2h[(size_t)s0 * NC + c];
        float f1 = (float)h2h[(size_t)s1 * NC + c];
        float f2 = (float)h2h[(size_t)s2 * NC + c];
        float f3 = (float)h2h[(size_t)s3 * NC + c];
        acc += w0 * f0 + w1 * f1 + w2 * f2 + w3 * f3;
        den += w0 + w1 + w2 + w3;
    }
    float o = acc / den + b2[c];
    float m = o;
    #pragma unroll
    for (int w = 1; w < 16; w <<= 1) m = fmaxf(m, __shfl_xor(m, w));
    float ex = __expf(o - m);
    float sm = ex;
    #pragma unroll
    for (int w = 1; w < 16; w <<= 1) sm += __shfl_xor(sm, w);
    out[(size_t)d * NC + c] = o - m - __logf(sm);
}

extern "C" void kernel_launch(void* const* d_in, const int* in_sizes, int n_in,
                              void* d_out, int out_size, void* d_ws, size_t ws_size,
                              hipStream_t stream) {
    const float* x   = (const float*)d_in[0];
    const int*   ei  = (const int*)  d_in[1];
    const float* W1  = (const float*)d_in[2];
    const float* as1 = (const float*)d_in[3];
    const float* ad1 = (const float*)d_in[4];
    const float* b1  = (const float*)d_in[5];
    const float* W2  = (const float*)d_in[6];
    const float* as2 = (const float*)d_in[7];
    const float* ad2 = (const float*)d_in[8];
    const float* b2  = (const float*)d_in[9];
    float* ws  = (float*)d_ws;
    float* out = (float*)d_out;

    __half*    h1h  = (__half*)(ws + OFF_H1H);
    _Float16*  g1h  = (_Float16*)(ws + OFF_G1H);
    _Float16*  h2h  = (_Float16*)(ws + OFF_H2H);
    float* als1 = ws + OFF_ALS1;
    float* ald1 = ws + OFF_ALD1;
    float* als2 = ws + OFF_ALS2;
    float* ald2 = ws + OFF_ALD2;
    int* H      = (int*)(ws + OFF_HM);
    int* basek  = (int*)(ws + OFF_BASEK);
    int* bbase  = (int*)(ws + OFF_BBASE);
    int* offs   = (int*)(ws + OFF_OFFS);
    int* ssrc   = (int*)(ws + OFF_SRC);
    int* stage  = (int*)(ws + OFF_STAGE);

    k_g1rh    <<<GB1 + CH,       256, 0, stream>>>(x, W1, as1, ad1, h1h, als1, ald1, ei, H);
    k_rsA     <<<NCB,            256, 0, stream>>>(H, basek, bbase + NCB + 2 /*btot*/);
    k_rsB     <<<1,              256, 0, stream>>>(bbase + NCB + 2, bbase, offs);
    k_rscatter<<<CH,             256, 0, stream>>>(ei, basek, bbase, stage);
    k_fsort   <<<NCB,            256, 0, stream>>>(stage, bbase, offs, ssrc);
    k_agg1    <<<(NN + 3) / 4,   256, 0, stream>>>(offs, ssrc, h1h, als1, ald1, b1, g1h);
    k_gemm2   <<<(NN + 15) / 16, 256, 0, stream>>>(g1h, W2, as2, ad2, h2h, als2, ald2);
    k_agg2    <<<(NN + 15) / 16, 256, 0, stream>>>(offs, ssrc, h2h, als2, ald2, b2, out);
}

// Round 12
// 137.849 us; speedup vs baseline: 1.0615x; 1.0014x over previous
//
#include <hip/hip_runtime.h>
#include <hip/hip_fp16.h>

#define NN   50000
#define FIN  256
#define C1   64        // HEADS*HID
#define NH   8
#define NC   16
#define NE   1600000
#define NTOT (NE + NN)

#define CH   256                        // pass-1 chunks
#define EPC  ((NTOT + CH - 1) / CH)     // 6446 edges per chunk
#define NCB  392                        // coarse buckets: dst>>7 (128 dsts each)
#define GB1  ((NN + 63) / 64)           // 782 gemm1 blocks

typedef _Float16 half8 __attribute__((ext_vector_type(8)));
typedef _Float16 half4 __attribute__((ext_vector_type(4)));
typedef float f32x4 __attribute__((ext_vector_type(4)));

// ---- workspace layout (float-indexed), ~36.4 MB ----
// h1h [0,1.6M) fp16 (g1rh->agg1) | g1h [1.6M,3.2M) fp16 (agg1->gemm2)
// stage [3.2M,4.85M) sort only (rscatter->fsort); after fsort reused:
//   h2h [3.2M,3.6M), als2 [3.6M,3.65M), ald2 [3.65M,3.7M)
// als1 [6.4M,6.8M) ald1 [6.8M,7.2M) | sort metadata >= 7.2M | w1t at end
#define OFF_H1H   0
#define OFF_G1H   1600000
#define OFF_STAGE 3200000
#define OFF_H2H   3200000
#define OFF_ALS2  3600000
#define OFF_ALD2  3650000
#define OFF_ALS1  6400000
#define OFF_ALD1  6800000
#define OFF_HM    7200000    // int H[CH*NCB] = 100352
#define OFF_BASEK 7300352    // int basek[NCB*CH] = 100352
#define OFF_BBASE 7400704    // int bbase[NCB+1]; btot at +400
#define OFF_OFFS  7401600    // int offs[NN+1]
#define OFF_SRC   7451700    // int ssrc[NTOT]
#define OFF_W1T   9101700    // fp16 W1T [64][256] = 8192 floats
// end = 9,109,892 floats = 36.4 MB

// ------- K0: W1 (256x64 f32) -> w1t fp16 [col][k] ----------
__global__ __launch_bounds__(256) void k_wcvt(const float* __restrict__ W1,
                                              _Float16* __restrict__ w1t) {
    int t = blockIdx.x * 256 + threadIdx.x;   // 64 blocks x 256 = 16384
    int c = t >> 8, k = t & 255;
    w1t[t] = (_Float16)W1[k * C1 + c];
}

// ------- K1: [blocks 0..781] h1=x@W1 MFMA (BK=32 pipelined)
//         [blocks 782..1037] rh: per-chunk coarse histogram
__global__ __launch_bounds__(256) void k_g1rh(const float* __restrict__ x,
                                              const _Float16* __restrict__ w1t,
                                              const float* __restrict__ as1,
                                              const float* __restrict__ ad1,
                                              __half* __restrict__ h1h,
                                              float* __restrict__ als,
                                              float* __restrict__ ald,
                                              const int* __restrict__ ei,
                                              int* __restrict__ H) {
    __shared__ _Float16 wsT[64][264];   // [col][k]  33.0 KB
    __shared__ _Float16 xs[64][40];     // [row][k-chunk 32]  5.0 KB (aliased as lh)
    const int tid = threadIdx.x;

    if (blockIdx.x >= GB1) {            // ---- rh branch ----
        int* lh = (int*)xs;             // 392 ints fit in xs (5120 B)
        int k = blockIdx.x - GB1;
        for (int i = tid; i < NCB; i += 256) lh[i] = 0;
        __syncthreads();
        int e0 = k * EPC, e1 = min(e0 + EPC, NTOT);
        for (int e = e0 + tid; e < e1; e += 256) {
            int d = (e < NE) ? ei[NE + e] : (e - NE);
            atomicAdd(&lh[d >> 7], 1);
        }
        __syncthreads();
        for (int i = tid; i < NCB; i += 256) H[k * NCB + i] = lh[i];
        return;
    }

    // ---- gemm1 branch ----
    const int r0 = blockIdx.x * 64;
    // stage w1t -> wsT: 8 coalesced half8 loads
    #pragma unroll
    for (int j = 0; j < 8; ++j) {
        int idx = tid * 8 + j * 2048;
        int c = idx >> 8, ko = idx & 255;
        *(half8*)(&wsT[c][ko]) = *(const half8*)(&w1t[idx]);
    }

    const int lane = tid & 63;
    const int wv   = tid >> 6;
    const int colb = lane & 15;
    const int rgrp = lane >> 4;
    f32x4 acc[4] = {};
    const int srow = tid >> 2;
    const int sq   = tid & 3;
    for (int k0 = 0; k0 < FIN; k0 += 32) {
        __syncthreads();
        {
            int grow = r0 + srow;
            float4 v0 = make_float4(0.f,0.f,0.f,0.f), v1 = v0;
            if (grow < NN) {
                const float4* xp = (const float4*)(&x[(size_t)grow * FIN + k0 + sq * 8]);
                v0 = xp[0]; v1 = xp[1];
            }
            half8 hv;
            hv[0]=(_Float16)v0.x; hv[1]=(_Float16)v0.y; hv[2]=(_Float16)v0.z; hv[3]=(_Float16)v0.w;
            hv[4]=(_Float16)v1.x; hv[5]=(_Float16)v1.y; hv[6]=(_Float16)v1.z; hv[7]=(_Float16)v1.w;
            *(half8*)(&xs[srow][sq * 8]) = hv;
        }
        __syncthreads();
        half8 a = *(half8*)(&xs[wv * 16 + colb][rgrp * 8]);
        #pragma unroll
        for (int ct = 0; ct < 4; ++ct) {
            half8 b = *(half8*)(&wsT[ct * 16 + colb][k0 + rgrp * 8]);
            acc[ct] = __builtin_amdgcn_mfma_f32_16x16x32_f16(a, b, acc[ct], 0, 0, 0);
        }
    }

    float a_s[4], a_d[4];
    #pragma unroll
    for (int ct = 0; ct < 4; ++ct) { a_s[ct] = as1[ct * 16 + colb]; a_d[ct] = ad1[ct * 16 + colb]; }
    #pragma unroll
    for (int j = 0; j < 4; ++j) {
        int row = r0 + wv * 16 + rgrp * 4 + j;
        bool rv = row < NN;
        #pragma unroll
        for (int ct = 0; ct < 4; ++ct) {
            if (rv) h1h[(size_t)row * C1 + ct * 16 + colb] = __float2half(acc[ct][j]);
            float p = acc[ct][j] * a_s[ct];
            p += __shfl_xor(p, 1); p += __shfl_xor(p, 2); p += __shfl_xor(p, 4);
            float q = acc[ct][j] * a_d[ct];
            q += __shfl_xor(q, 1); q += __shfl_xor(q, 2); q += __shfl_xor(q, 4);
            if (rv && (lane & 7) == 0) {
                int head = ct * 2 + (colb >> 3);
                als[row * NH + head] = p;
                ald[row * NH + head] = q;
            }
        }
    }
}

// ======== deterministic 2-pass counting sort (no global atomics) =========
__global__ __launch_bounds__(256) void k_rsA(const int* __restrict__ H,
                                             int* __restrict__ basek,
                                             int* __restrict__ btot) {
    __shared__ int sc[CH];
    int b = blockIdx.x, t = threadIdx.x;
    int v = H[t * NCB + b];
    sc[t] = v;
    __syncthreads();
    for (int s = 1; s < CH; s <<= 1) {
        int u = (t >= s) ? sc[t - s] : 0;
        __syncthreads();
        sc[t] += u;
        __syncthreads();
    }
    basek[b * CH + t] = sc[t] - v;
    if (t == CH - 1) btot[b] = sc[t];
}

// exclusive scan of 392 bucket totals (one 512-thread block)
__global__ __launch_bounds__(512) void k_rsB(const int* __restrict__ btot,
                                             int* __restrict__ bbase,
                                             int* __restrict__ offs) {
    __shared__ int sc[512];
    int t = threadIdx.x;
    int v = (t < NCB) ? btot[t] : 0;
    sc[t] = v;
    __syncthreads();
    for (int s = 1; s < 512; s <<= 1) {
        int u = (t >= s) ? sc[t - s] : 0;
        __syncthreads();
        sc[t] += u;
        __syncthreads();
    }
    if (t < NCB) bbase[t] = sc[t] - v;
    if (t == NCB - 1) bbase[NCB] = sc[t];
    if (t == 0) offs[NN] = NTOT;
}

__global__ __launch_bounds__(256) void k_rscatter(const int* __restrict__ ei,
                                                  const int* __restrict__ basek,
                                                  const int* __restrict__ bbase,
                                                  int* __restrict__ stage) {
    __shared__ int lcur[NCB];
    int k = blockIdx.x;
    for (int i = threadIdx.x; i < NCB; i += 256)
        lcur[i] = bbase[i] + basek[i * CH + k];
    __syncthreads();
    int e0 = k * EPC, e1 = min(e0 + EPC, NTOT);
    for (int e = e0 + threadIdx.x; e < e1; e += 256) {
        int s, d;
        if (e < NE) { s = ei[e]; d = ei[NE + e]; }
        else        { s = e - NE; d = s; }
        int pos = atomicAdd(&lcur[d >> 7], 1);
        stage[pos] = (s << 7) | (d & 127);
    }
}

__global__ __launch_bounds__(256) void k_fsort(const int* __restrict__ stage,
                                               const int* __restrict__ bbase,
                                               int* __restrict__ offs,
                                               int* __restrict__ ssrc) {
    __shared__ int lc[128];
    __shared__ int ls[128];
    __shared__ int lcur[128];
    int b = blockIdx.x, t = threadIdx.x;
    int base = bbase[b];
    int n = bbase[b + 1] - base;
    if (t < 128) lc[t] = 0;
    __syncthreads();
    const int* sp = &stage[base];
    for (int i = t; i < n; i += 256) atomicAdd(&lc[sp[i] & 127], 1);
    __syncthreads();
    int v = (t < 128) ? lc[t] : 0;
    if (t < 128) ls[t] = v;
    __syncthreads();
    for (int s = 1; s < 128; s <<= 1) {
        int u = (t >= s && t < 128) ? ls[t - s] : 0;
        __syncthreads();
        if (t < 128) ls[t] += u;
        __syncthreads();
    }
    if (t < 128) {
        int excl = ls[t] - v;
        int d = b * 128 + t;
        if (d < NN) offs[d] = base + excl;
        lcur[t] = base + excl;
    }
    __syncthreads();
    for (int i = t; i < n; i += 256) {
        int u = sp[i];
        int pos = atomicAdd(&lcur[u & 127], 1);
        ssrc[pos] = u >> 7;
    }
}

// ------- K2: layer-1 aggregation: quarter half4 gathers, 1-round pipeline,
//             32-bit byte-offset addressing -------------------------------
__global__ __launch_bounds__(256) void k_agg1(const int* __restrict__ offs,
                                              const int* __restrict__ src,
                                              const __half* __restrict__ h1h,
                                              const float* __restrict__ als,
                                              const float* __restrict__ ald,
                                              const float* __restrict__ b1,
                                              _Float16* __restrict__ g1h) {
    int d = blockIdx.x * 4 + (threadIdx.x >> 6);
    if (d >= NN) return;
    const int l  = threadIdx.x & 63;
    const int q  = l >> 4, lc = l & 15;
    const int hg = lc >> 1;
    const int sub = l >> 3, hw = l & 7;
    const int lane_a = (q << 3) | hg;
    const int lane_b = lane_a + 32;
    const unsigned coff = (unsigned)lc * 8u;       // byte offset of half4 in row
    const unsigned hoff = (unsigned)hw * 4u;       // byte offset in als row
    const char* h1b = (const char*)h1h;
    const char* alb = (const char*)als;
    int beg = offs[d], end = offs[d + 1];
    float aldv = ald[d * NH + hw];
    f32x4 acc = {0.f, 0.f, 0.f, 0.f};
    float wsum = 0.f;

    int r = beg;
    int e0 = r + sub, e1 = e0 + 8;
    int s0 = src[e0 < end ? e0 : end - 1];
    int s1 = src[e1 < end ? e1 : end - 1];
    while (r < end) {
        bool v0 = (r + sub) < end, v1 = (r + 8 + sub) < end;
        float lg0 = *(const float*)(alb + ((unsigned)s0 * 32u + hoff)) + aldv;
        float lg1 = *(const float*)(alb + ((unsigned)s1 * 32u + hoff)) + aldv;
        lg0 = lg0 > 0.f ? lg0 : 0.2f * lg0;
        lg1 = lg1 > 0.f ? lg1 : 0.2f * lg1;
        float w0 = v0 ? __expf(lg0) : 0.f;
        float w1 = v1 ? __expf(lg1) : 0.f;
        wsum += w0 + w1;
        int rn = r + 16;
        int s0n = s0, s1n = s1;
        if (rn < end) {          // preload next round (hides src->als->exp chain)
            int f0 = rn + sub, f1 = f0 + 8;
            s0n = src[f0 < end ? f0 : end - 1];
            s1n = src[f1 < end ? f1 : end - 1];
        }
        #pragma unroll
        for (int i = 0; i < 4; ++i) {
            int srcl = (i & 1) ? lane_b : lane_a;
            int sv   = __shfl((i < 2) ? s0 : s1, srcl);
            float wv = __shfl((i < 2) ? w0 : w1, srcl);
            half4 hv = *(const half4*)(h1b + ((unsigned)sv * 128u + coff));
            acc[0] += wv * (float)hv[0];
            acc[1] += wv * (float)hv[1];
            acc[2] += wv * (float)hv[2];
            acc[3] += wv * (float)hv[3];
        }
        s0 = s0n; s1 = s1n; r = rn;
    }
    #pragma unroll
    for (int k = 0; k < 4; ++k) {
        acc[k] += __shfl_xor(acc[k], 16);
        acc[k] += __shfl_xor(acc[k], 32);
    }
    // wsum: reduce over lanes sharing hw (stride-8 group), then fetch den(hg)
    wsum += __shfl_xor(wsum, 8);
    wsum += __shfl_xor(wsum, 16);
    wsum += __shfl_xor(wsum, 32);
    float den = __shfl(wsum, hg);
    if (q == 0) {
        half4 gv;
        #pragma unroll
        for (int k = 0; k < 4; ++k) {
            float o = acc[k] / den + b1[4 * lc + k];
            o = o > 0.f ? o : (__expf(o) - 1.f);
            gv[k] = (_Float16)o;
        }
        *(half4*)(&g1h[(size_t)d * C1 + 4 * lc]) = gv;
    }
}

// ---------------- K3: GEMM2 (64->16, fp16 in) + layer-2 logits ----------------
__global__ __launch_bounds__(256) void k_gemm2(const _Float16* __restrict__ g1h,
                                               const float* __restrict__ W2,
                                               const float* __restrict__ as2,
                                               const float* __restrict__ ad2,
                                               _Float16* __restrict__ h2h,
                                               float* __restrict__ als2,
                                               float* __restrict__ ald2) {
    __shared__ float w2s[C1][17];
    __shared__ _Float16 hact[16][C1 + 8];
    int tid = threadIdx.x;
    for (int i = tid; i < C1 * NC; i += 256) w2s[i >> 4][i & 15] = W2[i];
    int ln = tid >> 4, j = tid & 15;
    int n = blockIdx.x * 16 + ln;
    if (n < NN)
        *(half4*)(&hact[ln][j * 4]) = *(const half4*)(&g1h[(size_t)n * C1 + j * 4]);
    __syncthreads();
    if (n >= NN) return;
    float sum = 0.f;
    #pragma unroll
    for (int c = 0; c < C1; ++c) sum += (float)hact[ln][c] * w2s[c][j];
    h2h[(size_t)n * NC + j] = (_Float16)sum;
    float ps = sum * as2[j], pd = sum * ad2[j];
    #pragma unroll
    for (int w = 1; w < 16; w <<= 1) {
        ps += __shfl_xor(ps, w);
        pd += __shfl_xor(pd, w);
    }
    if (j == 0) { als2[n] = ps; ald2[n] = pd; }
}

// ------- K4: layer-2 aggregation (fp16 h2), 16 lanes/dst, 8-edge ILP ------
__global__ __launch_bounds__(256) void k_agg2(const int* __restrict__ offs,
                                              const int* __restrict__ src,
                                              const _Float16* __restrict__ h2h,
                                              const float* __restrict__ als2,
                                              const float* __restrict__ ald2,
                                              const float* __restrict__ b2,
                                              float* __restrict__ out) {
    int d = blockIdx.x * 16 + (threadIdx.x >> 4);
    if (d >= NN) return;
    int c = threadIdx.x & 15;
    const unsigned coff = (unsigned)c * 2u;
    const char* h2b = (const char*)h2h;
    const char* alb = (const char*)als2;
    int beg = offs[d], end = offs[d + 1];
    float aldv = ald2[d];
    float acc = 0.f, den = 0.f;
    for (int r = beg; r < end; r += 8) {
        int ss[8];
        float ww[8];
        #pragma unroll
        for (int i = 0; i < 8; ++i) {
            int e = r + i;
            ss[i] = src[e < end ? e : end - 1];
        }
        #pragma unroll
        for (int i = 0; i < 8; ++i) {
            float lg = *(const float*)(alb + (unsigned)ss[i] * 4u) + aldv;
            lg = lg > 0.f ? lg : 0.2f * lg;
            ww[i] = (r + i) < end ? __expf(lg) : 0.f;
        }
        #pragma unroll
        for (int i = 0; i < 8; ++i) {
            float hv = (float)*(const _Float16*)(h2b + ((unsigned)ss[i] * 32u + coff));
            acc += ww[i] * hv;
            den += ww[i];
        }
    }
    float o = acc / den + b2[c];
    float m = o;
    #pragma unroll
    for (int w = 1; w < 16; w <<= 1) m = fmaxf(m, __shfl_xor(m, w));
    float ex = __expf(o - m);
    float sm = ex;
    #pragma unroll
    for (int w = 1; w < 16; w <<= 1) sm += __shfl_xor(sm, w);
    out[(size_t)d * NC + c] = o - m - __logf(sm);
}

extern "C" void kernel_launch(void* const* d_in, const int* in_sizes, int n_in,
                              void* d_out, int out_size, void* d_ws, size_t ws_size,
                              hipStream_t stream) {
    const float* x   = (const float*)d_in[0];
    const int*   ei  = (const int*)  d_in[1];
    const float* W1  = (const float*)d_in[2];
    const float* as1 = (const float*)d_in[3];
    const float* ad1 = (const float*)d_in[4];
    const float* b1  = (const float*)d_in[5];
    const float* W2  = (const float*)d_in[6];
    const float* as2 = (const float*)d_in[7];
    const float* ad2 = (const float*)d_in[8];
    const float* b2  = (const float*)d_in[9];
    float* ws  = (float*)d_ws;
    float* out = (float*)d_out;

    __half*    h1h  = (__half*)(ws + OFF_H1H);
    _Float16*  g1h  = (_Float16*)(ws + OFF_G1H);
    _Float16*  h2h  = (_Float16*)(ws + OFF_H2H);
    _Float16*  w1t  = (_Float16*)(ws + OFF_W1T);
    float* als1 = ws + OFF_ALS1;
    float* ald1 = ws + OFF_ALD1;
    float* als2 = ws + OFF_ALS2;
    float* ald2 = ws + OFF_ALD2;
    int* H      = (int*)(ws + OFF_HM);
    int* basek  = (int*)(ws + OFF_BASEK);
    int* bbase  = (int*)(ws + OFF_BBASE);
    int* btot   = (int*)(ws + OFF_BBASE) + 400;
    int* offs   = (int*)(ws + OFF_OFFS);
    int* ssrc   = (int*)(ws + OFF_SRC);
    int* stage  = (int*)(ws + OFF_STAGE);

    k_wcvt    <<<64,             256, 0, stream>>>(W1, w1t);
    k_g1rh    <<<GB1 + CH,       256, 0, stream>>>(x, w1t, as1, ad1, h1h, als1, ald1, ei, H);
    k_rsA     <<<NCB,            256, 0, stream>>>(H, basek, btot);
    k_rsB     <<<1,              512, 0, stream>>>(btot, bbase, offs);
    k_rscatter<<<CH,             256, 0, stream>>>(ei, basek, bbase, stage);
    k_fsort   <<<NCB,            256, 0, stream>>>(stage, bbase, offs, ssrc);
    k_agg1    <<<(NN + 3) / 4,   256, 0, stream>>>(offs, ssrc, h1h, als1, ald1, b1, g1h);
    k_gemm2   <<<(NN + 15) / 16, 256, 0, stream>>>(g1h, W2, as2, ad2, h2h, als2, ald2);
    k_agg2    <<<(NN + 15) / 16, 256, 0, stream>>>(offs, ssrc, h2h, als2, ald2, b2, out);
}

// Round 13
// 137.423 us; speedup vs baseline: 1.0648x; 1.0031x over previous
//
#include <hip/hip_runtime.h>
#include <hip/hip_fp16.h>

#define NN   50000
#define FIN  256
#define C1   64        // HEADS*HID
#define NH   8
#define NC   16
#define NE   1600000
#define NTOT (NE + NN)

#define CH   256                        // pass-1 chunks
#define EPC  ((NTOT + CH - 1) / CH)     // 6446 edges per chunk
#define NCB  392                        // coarse buckets: dst>>7 (128 dsts each)
#define GB1  ((NN + 63) / 64)           // 782 gemm1 blocks

typedef _Float16 half8 __attribute__((ext_vector_type(8)));
typedef _Float16 half4 __attribute__((ext_vector_type(4)));
typedef float f32x4 __attribute__((ext_vector_type(4)));

// ---- workspace layout (float-indexed), ~36.4 MB (d_ws is 256 MiB) ----
// h1h [0,1.6M) fp16 (g1rh->agg1) | g1h [1.6M,3.2M) fp16 (agg1->gemm2)
// stage [3.2M,4.85M) sort only (rscatter->fsort); after fsort reused:
//   h2h [3.2M,3.6M), als2 [3.6M,3.65M), ald2 [3.65M,3.7M)
// als1 [6.4M,6.8M) ald1 [6.8M,7.2M) | sort metadata >= 7.2M | w1t at end
#define OFF_H1H   0
#define OFF_G1H   1600000
#define OFF_STAGE 3200000
#define OFF_H2H   3200000
#define OFF_ALS2  3600000
#define OFF_ALD2  3650000
#define OFF_ALS1  6400000
#define OFF_ALD1  6800000
#define OFF_HM    7200000    // int H[CH*NCB]
#define OFF_BASEK 7300352    // int basek[NCB*CH]
#define OFF_BBASE 7400704    // int bbase[NCB+1]; btot at +400
#define OFF_OFFS  7401600    // int offs[NN+1]
#define OFF_SRC   7451700    // int ssrc[NTOT]
#define OFF_W1T   9101700    // fp16 W1T [64][256]
// end = 9,109,892 floats = 36.4 MB

// ------- K0: W1 (256x64 f32) -> w1t fp16 [col][k] ----------
__global__ __launch_bounds__(256) void k_wcvt(const float* __restrict__ W1,
                                              _Float16* __restrict__ w1t) {
    int t = blockIdx.x * 256 + threadIdx.x;
    int c = t >> 8, k = t & 255;
    w1t[t] = (_Float16)W1[k * C1 + c];
}

// ------- K1: [blocks 0..781] h1=x@W1 MFMA, A direct-to-register, 3 barriers
//         [blocks 782..1037] rh: per-chunk coarse histogram
__global__ __launch_bounds__(256) void k_g1rh(const float* __restrict__ x,
                                              const _Float16* __restrict__ w1t,
                                              const float* __restrict__ as1,
                                              const float* __restrict__ ad1,
                                              _Float16* __restrict__ h1h,
                                              float* __restrict__ als,
                                              float* __restrict__ ald,
                                              const int* __restrict__ ei,
                                              int* __restrict__ H) {
    __shared__ _Float16 wsT[64][264];   // [col][k] 33.8 KB; reused as hstore
    __shared__ int lh[NCB];             // 1.6 KB (rh branch only)
    const int tid = threadIdx.x;

    if (blockIdx.x >= GB1) {            // ---- rh branch ----
        int k = blockIdx.x - GB1;
        for (int i = tid; i < NCB; i += 256) lh[i] = 0;
        __syncthreads();
        int e0 = k * EPC, e1 = min(e0 + EPC, NTOT);
        for (int e = e0 + tid; e < e1; e += 256) {
            int d = (e < NE) ? ei[NE + e] : (e - NE);
            atomicAdd(&lh[d >> 7], 1);
        }
        __syncthreads();
        for (int i = tid; i < NCB; i += 256) H[k * NCB + i] = lh[i];
        return;
    }

    // ---- gemm1 branch ----
    const int r0 = blockIdx.x * 64;
    #pragma unroll
    for (int j = 0; j < 8; ++j) {       // stage w1t -> wsT, coalesced half8
        int idx = tid * 8 + j * 2048;
        int c = idx >> 8, ko = idx & 255;
        *(half8*)(&wsT[c][ko]) = *(const half8*)(&w1t[idx]);
    }
    __syncthreads();

    const int lane = tid & 63;
    const int wv   = tid >> 6;
    const int colb = lane & 15;
    const int rgrp = lane >> 4;
    const int arow = r0 + wv * 16 + colb;     // A row this lane supplies
    const bool arv = arow < NN;
    f32x4 acc[4] = {};
    #pragma unroll
    for (int s = 0; s < 8; ++s) {
        float4 v0 = make_float4(0.f,0.f,0.f,0.f), v1 = v0;
        if (arv) {
            const float4* xp = (const float4*)(&x[(size_t)arow * FIN + s * 32 + rgrp * 8]);
            v0 = xp[0]; v1 = xp[1];
        }
        half8 a;
        a[0]=(_Float16)v0.x; a[1]=(_Float16)v0.y; a[2]=(_Float16)v0.z; a[3]=(_Float16)v0.w;
        a[4]=(_Float16)v1.x; a[5]=(_Float16)v1.y; a[6]=(_Float16)v1.z; a[7]=(_Float16)v1.w;
        #pragma unroll
        for (int ct = 0; ct < 4; ++ct) {
            half8 b = *(half8*)(&wsT[ct * 16 + colb][s * 32 + rgrp * 8]);
            acc[ct] = __builtin_amdgcn_mfma_f32_16x16x32_f16(a, b, acc[ct], 0, 0, 0);
        }
    }
    __syncthreads();                    // all wsT reads done; reuse as hstore
    _Float16 (*hstore)[72] = (_Float16(*)[72])wsT;
    #pragma unroll
    for (int j = 0; j < 4; ++j) {
        int row = wv * 16 + rgrp * 4 + j;
        #pragma unroll
        for (int ct = 0; ct < 4; ++ct)
            hstore[row][ct * 16 + colb] = (_Float16)acc[ct][j];
    }
    __syncthreads();
    {   // coalesced h1h store + lane-local als/ald (2 heads per lane)
        int row = tid >> 2, seg = tid & 3;
        int grow = r0 + row;
        if (grow < NN) {
            half8 h0 = *(half8*)(&hstore[row][seg * 16]);
            half8 h1v = *(half8*)(&hstore[row][seg * 16 + 8]);
            *(half8*)(&h1h[(size_t)grow * C1 + seg * 16])     = h0;
            *(half8*)(&h1h[(size_t)grow * C1 + seg * 16 + 8]) = h1v;
            float ps0 = 0.f, pd0 = 0.f, ps1 = 0.f, pd1 = 0.f;
            #pragma unroll
            for (int u = 0; u < 8; ++u) {
                float a0 = (float)h0[u], a1 = (float)h1v[u];
                ps0 += a0 * as1[seg * 16 + u];
                pd0 += a0 * ad1[seg * 16 + u];
                ps1 += a1 * as1[seg * 16 + 8 + u];
                pd1 += a1 * ad1[seg * 16 + 8 + u];
            }
            als[grow * NH + seg * 2]     = ps0;
            als[grow * NH + seg * 2 + 1] = ps1;
            ald[grow * NH + seg * 2]     = pd0;
            ald[grow * NH + seg * 2 + 1] = pd1;
        }
    }
}

// ======== deterministic 2-pass counting sort (no global atomics) =========
__global__ __launch_bounds__(256) void k_rsA(const int* __restrict__ H,
                                             int* __restrict__ basek,
                                             int* __restrict__ btot) {
    __shared__ int sc[CH];
    int b = blockIdx.x, t = threadIdx.x;
    int v = H[t * NCB + b];
    sc[t] = v;
    __syncthreads();
    for (int s = 1; s < CH; s <<= 1) {
        int u = (t >= s) ? sc[t - s] : 0;
        __syncthreads();
        sc[t] += u;
        __syncthreads();
    }
    basek[b * CH + t] = sc[t] - v;
    if (t == CH - 1) btot[b] = sc[t];
}

__global__ __launch_bounds__(512) void k_rsB(const int* __restrict__ btot,
                                             int* __restrict__ bbase,
                                             int* __restrict__ offs) {
    __shared__ int sc[512];
    int t = threadIdx.x;
    int v = (t < NCB) ? btot[t] : 0;
    sc[t] = v;
    __syncthreads();
    for (int s = 1; s < 512; s <<= 1) {
        int u = (t >= s) ? sc[t - s] : 0;
        __syncthreads();
        sc[t] += u;
        __syncthreads();
    }
    if (t < NCB) bbase[t] = sc[t] - v;
    if (t == NCB - 1) bbase[NCB] = sc[t];
    if (t == 0) offs[NN] = NTOT;
}

__global__ __launch_bounds__(256) void k_rscatter(const int* __restrict__ ei,
                                                  const int* __restrict__ basek,
                                                  const int* __restrict__ bbase,
                                                  int* __restrict__ stage) {
    __shared__ int lcur[NCB];
    int k = blockIdx.x;
    for (int i = threadIdx.x; i < NCB; i += 256)
        lcur[i] = bbase[i] + basek[i * CH + k];
    __syncthreads();
    int e0 = k * EPC, e1 = min(e0 + EPC, NTOT);
    for (int e = e0 + threadIdx.x; e < e1; e += 256) {
        int s, d;
        if (e < NE) { s = ei[e]; d = ei[NE + e]; }
        else        { s = e - NE; d = s; }
        int pos = atomicAdd(&lcur[d >> 7], 1);
        stage[pos] = (s << 7) | (d & 127);
    }
}

__global__ __launch_bounds__(256) void k_fsort(const int* __restrict__ stage,
                                               const int* __restrict__ bbase,
                                               int* __restrict__ offs,
                                               int* __restrict__ ssrc) {
    __shared__ int lc[128];
    __shared__ int ls[128];
    __shared__ int lcur[128];
    int b = blockIdx.x, t = threadIdx.x;
    int base = bbase[b];
    int n = bbase[b + 1] - base;
    if (t < 128) lc[t] = 0;
    __syncthreads();
    const int* sp = &stage[base];
    for (int i = t; i < n; i += 256) atomicAdd(&lc[sp[i] & 127], 1);
    __syncthreads();
    int v = (t < 128) ? lc[t] : 0;
    if (t < 128) ls[t] = v;
    __syncthreads();
    for (int s = 1; s < 128; s <<= 1) {
        int u = (t >= s && t < 128) ? ls[t - s] : 0;
        __syncthreads();
        if (t < 128) ls[t] += u;
        __syncthreads();
    }
    if (t < 128) {
        int excl = ls[t] - v;
        int d = b * 128 + t;
        if (d < NN) offs[d] = base + excl;
        lcur[t] = base + excl;
    }
    __syncthreads();
    for (int i = t; i < n; i += 256) {
        int u = sp[i];
        int pos = atomicAdd(&lcur[u & 127], 1);
        ssrc[pos] = u >> 7;
    }
}

// ------- K2: layer-1 aggregation: quarter half4 gathers, FULL weight
//             software-pipeline (src+als+exp for round r+1 overlap gathers) --
__global__ __launch_bounds__(256) void k_agg1(const int* __restrict__ offs,
                                              const int* __restrict__ src,
                                              const __half* __restrict__ h1h,
                                              const float* __restrict__ als,
                                              const float* __restrict__ ald,
                                              const float* __restrict__ b1,
                                              _Float16* __restrict__ g1h) {
    int d = blockIdx.x * 4 + (threadIdx.x >> 6);
    if (d >= NN) return;
    const int l  = threadIdx.x & 63;
    const int q  = l >> 4, lc = l & 15;
    const int hg = lc >> 1;
    const int sub = l >> 3, hw = l & 7;
    const int lane_a = (q << 3) | hg;
    const int lane_b = lane_a + 32;
    const unsigned coff = (unsigned)lc * 8u;
    const unsigned hoff = (unsigned)hw * 4u;
    const char* h1b = (const char*)h1h;
    const char* alb = (const char*)als;
    int beg = offs[d], end = offs[d + 1];
    float aldv = ald[d * NH + hw];
    f32x4 acc = {0.f, 0.f, 0.f, 0.f};
    float wsum = 0.f;

    // prologue: round-0 src + weights
    int r = beg;
    int e0 = r + sub, e1 = e0 + 8;
    int s0 = src[e0 < end ? e0 : end - 1];
    int s1 = src[e1 < end ? e1 : end - 1];
    {
        float lg0 = *(const float*)(alb + ((unsigned)s0 * 32u + hoff)) + aldv;
        float lg1 = *(const float*)(alb + ((unsigned)s1 * 32u + hoff)) + aldv;
        lg0 = lg0 > 0.f ? lg0 : 0.2f * lg0;
        lg1 = lg1 > 0.f ? lg1 : 0.2f * lg1;
        s0 = e0 < end ? s0 : s0;  // keep
        // zero weights for invalid slots
        float w0t = e0 < end ? __expf(lg0) : 0.f;
        float w1t = e1 < end ? __expf(lg1) : 0.f;
        // store into loop-carried regs
        acc[0] = acc[0];  // no-op
        // use local vars below
        float w0 = w0t, w1 = w1t;
        while (r < end) {
            int rn = r + 16;
            bool more = rn < end;
            int s0n = s0, s1n = s1;
            if (more) {
                int f0 = rn + sub, f1 = f0 + 8;
                s0n = src[f0 < end ? f0 : end - 1];
                s1n = src[f1 < end ? f1 : end - 1];
            }
            wsum += w0 + w1;
            #pragma unroll
            for (int i = 0; i < 4; ++i) {
                int srcl = (i & 1) ? lane_b : lane_a;
                int sv   = __shfl((i < 2) ? s0 : s1, srcl);
                float wv = __shfl((i < 2) ? w0 : w1, srcl);
                half4 hv = *(const half4*)(h1b + ((unsigned)sv * 128u + coff));
                acc[0] += wv * (float)hv[0];
                acc[1] += wv * (float)hv[1];
                acc[2] += wv * (float)hv[2];
                acc[3] += wv * (float)hv[3];
            }
            if (more) {
                float g0 = *(const float*)(alb + ((unsigned)s0n * 32u + hoff)) + aldv;
                float g1 = *(const float*)(alb + ((unsigned)s1n * 32u + hoff)) + aldv;
                g0 = g0 > 0.f ? g0 : 0.2f * g0;
                g1 = g1 > 0.f ? g1 : 0.2f * g1;
                w0 = (rn + sub) < end ? __expf(g0) : 0.f;
                w1 = (rn + 8 + sub) < end ? __expf(g1) : 0.f;
            }
            s0 = s0n; s1 = s1n; r = rn;
        }
    }
    #pragma unroll
    for (int k = 0; k < 4; ++k) {
        acc[k] += __shfl_xor(acc[k], 16);
        acc[k] += __shfl_xor(acc[k], 32);
    }
    wsum += __shfl_xor(wsum, 8);
    wsum += __shfl_xor(wsum, 16);
    wsum += __shfl_xor(wsum, 32);
    float den = __shfl(wsum, hg);
    if (q == 0) {
        half4 gv;
        #pragma unroll
        for (int k = 0; k < 4; ++k) {
            float o = acc[k] / den + b1[4 * lc + k];
            o = o > 0.f ? o : (__expf(o) - 1.f);
            gv[k] = (_Float16)o;
        }
        *(half4*)(&g1h[(size_t)d * C1 + 4 * lc]) = gv;
    }
}

// ---------------- K3: GEMM2 (64->16, fp16 in) + layer-2 logits ----------------
__global__ __launch_bounds__(256) void k_gemm2(const _Float16* __restrict__ g1h,
                                               const float* __restrict__ W2,
                                               const float* __restrict__ as2,
                                               const float* __restrict__ ad2,
                                               _Float16* __restrict__ h2h,
                                               float* __restrict__ als2,
                                               float* __restrict__ ald2) {
    __shared__ float w2s[C1][17];
    __shared__ _Float16 hact[16][C1 + 8];
    int tid = threadIdx.x;
    for (int i = tid; i < C1 * NC; i += 256) w2s[i >> 4][i & 15] = W2[i];
    int ln = tid >> 4, j = tid & 15;
    int n = blockIdx.x * 16 + ln;
    if (n < NN)
        *(half4*)(&hact[ln][j * 4]) = *(const half4*)(&g1h[(size_t)n * C1 + j * 4]);
    __syncthreads();
    if (n >= NN) return;
    float sum = 0.f;
    #pragma unroll
    for (int c = 0; c < C1; ++c) sum += (float)hact[ln][c] * w2s[c][j];
    h2h[(size_t)n * NC + j] = (_Float16)sum;
    float ps = sum * as2[j], pd = sum * ad2[j];
    #pragma unroll
    for (int w = 1; w < 16; w <<= 1) {
        ps += __shfl_xor(ps, w);
        pd += __shfl_xor(pd, w);
    }
    if (j == 0) { als2[n] = ps; ald2[n] = pd; }
}

// ------- K4: layer-2 aggregation (fp16 h2), 16 lanes/dst, 8-edge ILP ------
__global__ __launch_bounds__(256) void k_agg2(const int* __restrict__ offs,
                                              const int* __restrict__ src,
                                              const _Float16* __restrict__ h2h,
                                              const float* __restrict__ als2,
                                              const float* __restrict__ ald2,
                                              const float* __restrict__ b2,
                                              float* __restrict__ out) {
    int d = blockIdx.x * 16 + (threadIdx.x >> 4);
    if (d >= NN) return;
    int c = threadIdx.x & 15;
    const unsigned coff = (unsigned)c * 2u;
    const char* h2b = (const char*)h2h;
    const char* alb = (const char*)als2;
    int beg = offs[d], end = offs[d + 1];
    float aldv = ald2[d];
    float acc = 0.f, den = 0.f;
    for (int r = beg; r < end; r += 8) {
        int ss[8];
        float ww[8];
        #pragma unroll
        for (int i = 0; i < 8; ++i) {
            int e = r + i;
            ss[i] = src[e < end ? e : end - 1];
        }
        #pragma unroll
        for (int i = 0; i < 8; ++i) {
            float lg = *(const float*)(alb + (unsigned)ss[i] * 4u) + aldv;
            lg = lg > 0.f ? lg : 0.2f * lg;
            ww[i] = (r + i) < end ? __expf(lg) : 0.f;
        }
        #pragma unroll
        for (int i = 0; i < 8; ++i) {
            float hv = (float)*(const _Float16*)(h2b + ((unsigned)ss[i] * 32u + coff));
            acc += ww[i] * hv;
            den += ww[i];
        }
    }
    float o = acc / den + b2[c];
    float m = o;
    #pragma unroll
    for (int w = 1; w < 16; w <<= 1) m = fmaxf(m, __shfl_xor(m, w));
    float ex = __expf(o - m);
    float sm = ex;
    #pragma unroll
    for (int w = 1; w < 16; w <<= 1) sm += __shfl_xor(sm, w);
    out[(size_t)d * NC + c] = o - m - __logf(sm);
}

extern "C" void kernel_launch(void* const* d_in, const int* in_sizes, int n_in,
                              void* d_out, int out_size, void* d_ws, size_t ws_size,
                              hipStream_t stream) {
    const float* x   = (const float*)d_in[0];
    const int*   ei  = (const int*)  d_in[1];
    const float* W1  = (const float*)d_in[2];
    const float* as1 = (const float*)d_in[3];
    const float* ad1 = (const float*)d_in[4];
    const float* b1  = (const float*)d_in[5];
    const float* W2  = (const float*)d_in[6];
    const float* as2 = (const float*)d_in[7];
    const float* ad2 = (const float*)d_in[8];
    const float* b2  = (const float*)d_in[9];
    float* ws  = (float*)d_ws;
    float* out = (float*)d_out;

    _Float16*  h1h  = (_Float16*)(ws + OFF_H1H);
    _Float16*  g1h  = (_Float16*)(ws + OFF_G1H);
    _Float16*  h2h  = (_Float16*)(ws + OFF_H2H);
    _Float16*  w1t  = (_Float16*)(ws + OFF_W1T);
    float* als1 = ws + OFF_ALS1;
    float* ald1 = ws + OFF_ALD1;
    float* als2 = ws + OFF_ALS2;
    float* ald2 = ws + OFF_ALD2;
    int* H      = (int*)(ws + OFF_HM);
    int* basek  = (int*)(ws + OFF_BASEK);
    int* bbase  = (int*)(ws + OFF_BBASE);
    int* btot   = (int*)(ws + OFF_BBASE) + 400;
    int* offs   = (int*)(ws + OFF_OFFS);
    int* ssrc   = (int*)(ws + OFF_SRC);
    int* stage  = (int*)(ws + OFF_STAGE);

    k_wcvt    <<<64,             256, 0, stream>>>(W1, w1t);
    k_g1rh    <<<GB1 + CH,       256, 0, stream>>>(x, w1t, as1, ad1, h1h, als1, ald1, ei, H);
    k_rsA     <<<NCB,            256, 0, stream>>>(H, basek, btot);
    k_rsB     <<<1,              512, 0, stream>>>(btot, bbase, offs);
    k_rscatter<<<CH,             256, 0, stream>>>(ei, basek, bbase, stage);
    k_fsort   <<<NCB,            256, 0, stream>>>(stage, bbase, offs, ssrc);
    k_agg1    <<<(NN + 3) / 4,   256, 0, stream>>>(offs, ssrc, (const __half*)h1h, als1, ald1, b1, g1h);
    k_gemm2   <<<(NN + 15) / 16, 256, 0, stream>>>(g1h, W2, as2, ad2, h2h, als2, ald2);
    k_agg2    <<<(NN + 15) / 16, 256, 0, stream>>>(offs, ssrc, h2h, als2, ald2, b2, out);
}

// Round 14
// 135.942 us; speedup vs baseline: 1.0764x; 1.0109x over previous
//
#include <hip/hip_runtime.h>
#include <hip/hip_fp16.h>

#define NN   50000
#define FIN  256
#define C1   64        // HEADS*HID
#define NH   8
#define NC   16
#define NE   1600000
#define NTOT (NE + NN)

#define CH   256                        // pass-1 chunks
#define EPC  ((NTOT + CH - 1) / CH)     // 6446 edges per chunk
#define NCB  196                        // coarse buckets: dst>>8 (256 dsts each)
#define GB1  ((NN + 63) / 64)           // 782 gemm1 blocks

typedef _Float16 half8 __attribute__((ext_vector_type(8)));
typedef _Float16 half4 __attribute__((ext_vector_type(4)));
typedef float f32x4 __attribute__((ext_vector_type(4)));

// ---- workspace layout (float-indexed), ~36.4 MB (d_ws is 256 MiB) ----
// h1h [0,1.6M) fp16 (g1rh->agg1) | g1h [1.6M,3.2M) fp16 (agg1->gemm2)
// stage [3.2M,4.85M) sort only; after fsort reused: h2h [3.2M,3.6M),
//   als2 [3.6M,3.65M), ald2 [3.65M,3.7M)
// als1 [6.4M,6.8M) ald1 [6.8M,7.2M) | sort metadata >= 7.2M
#define OFF_H1H   0
#define OFF_G1H   1600000
#define OFF_STAGE 3200000
#define OFF_H2H   3200000
#define OFF_ALS2  3600000
#define OFF_ALD2  3650000
#define OFF_ALS1  6400000
#define OFF_ALD1  6800000
#define OFF_HM    7200000    // int H[CH*NCB] = 50176
#define OFF_BASEK 7300352    // int basek[NCB*CH] = 50176
#define OFF_BTOT  7400704    // int btot[NCB]
#define OFF_OFFS  7401600    // int offs[NN+1]
#define OFF_SRC   7451700    // int ssrc[NTOT]
// end = 9,101,700 floats = 36.4 MB

// ------- K1: [blocks 0..781] h1=x@W1 MFMA, A direct-to-register
//         [blocks 782..1037] rh: per-chunk coarse histogram
__global__ __launch_bounds__(256) void k_g1rh(const float* __restrict__ x,
                                              const float* __restrict__ W1,
                                              const float* __restrict__ as1,
                                              const float* __restrict__ ad1,
                                              _Float16* __restrict__ h1h,
                                              float* __restrict__ als,
                                              float* __restrict__ ald,
                                              const int* __restrict__ ei,
                                              int* __restrict__ H) {
    __shared__ _Float16 wsT[64][264];   // [col][k] 33.8 KB; reused as hstore
    __shared__ int lh[NCB];
    const int tid = threadIdx.x;

    if (blockIdx.x >= GB1) {            // ---- rh branch ----
        int k = blockIdx.x - GB1;
        for (int i = tid; i < NCB; i += 256) lh[i] = 0;
        __syncthreads();
        int e0 = k * EPC, e1 = min(e0 + EPC, NTOT);
        for (int e = e0 + tid; e < e1; e += 256) {
            int d = (e < NE) ? ei[NE + e] : (e - NE);
            atomicAdd(&lh[d >> 8], 1);
        }
        __syncthreads();
        for (int i = tid; i < NCB; i += 256) H[k * NCB + i] = lh[i];
        return;
    }

    // ---- gemm1 branch ----
    const int r0 = blockIdx.x * 64;
    {   // stage W1 -> wsT[col][k], coalesced f32 reads, half8 writes
        int c = tid & 63, kb = tid >> 6;
        #pragma unroll
        for (int j = 0; j < 8; ++j) {
            int k8 = kb + 4 * j;
            half8 hv;
            #pragma unroll
            for (int u = 0; u < 8; ++u)
                hv[u] = (_Float16)W1[(size_t)(k8 * 8 + u) * C1 + c];
            *(half8*)(&wsT[c][k8 * 8]) = hv;
        }
    }
    __syncthreads();

    const int lane = tid & 63;
    const int wv   = tid >> 6;
    const int colb = lane & 15;
    const int rgrp = lane >> 4;
    const int arow = r0 + wv * 16 + colb;
    const bool arv = arow < NN;
    f32x4 acc[4] = {};
    #pragma unroll
    for (int s = 0; s < 8; ++s) {
        float4 v0 = make_float4(0.f,0.f,0.f,0.f), v1 = v0;
        if (arv) {
            const float4* xp = (const float4*)(&x[(size_t)arow * FIN + s * 32 + rgrp * 8]);
            v0 = xp[0]; v1 = xp[1];
        }
        half8 a;
        a[0]=(_Float16)v0.x; a[1]=(_Float16)v0.y; a[2]=(_Float16)v0.z; a[3]=(_Float16)v0.w;
        a[4]=(_Float16)v1.x; a[5]=(_Float16)v1.y; a[6]=(_Float16)v1.z; a[7]=(_Float16)v1.w;
        #pragma unroll
        for (int ct = 0; ct < 4; ++ct) {
            half8 b = *(half8*)(&wsT[ct * 16 + colb][s * 32 + rgrp * 8]);
            acc[ct] = __builtin_amdgcn_mfma_f32_16x16x32_f16(a, b, acc[ct], 0, 0, 0);
        }
    }
    __syncthreads();                    // wsT reads done; reuse as hstore
    _Float16 (*hstore)[72] = (_Float16(*)[72])wsT;
    #pragma unroll
    for (int j = 0; j < 4; ++j) {
        int row = wv * 16 + rgrp * 4 + j;
        #pragma unroll
        for (int ct = 0; ct < 4; ++ct)
            hstore[row][ct * 16 + colb] = (_Float16)acc[ct][j];
    }
    __syncthreads();
    {   // coalesced h1h store + lane-local als/ald (2 heads per lane)
        int row = tid >> 2, seg = tid & 3;
        int grow = r0 + row;
        if (grow < NN) {
            half8 h0 = *(half8*)(&hstore[row][seg * 16]);
            half8 h1v = *(half8*)(&hstore[row][seg * 16 + 8]);
            *(half8*)(&h1h[(size_t)grow * C1 + seg * 16])     = h0;
            *(half8*)(&h1h[(size_t)grow * C1 + seg * 16 + 8]) = h1v;
            float ps0 = 0.f, pd0 = 0.f, ps1 = 0.f, pd1 = 0.f;
            #pragma unroll
            for (int u = 0; u < 8; ++u) {
                float a0 = (float)h0[u], a1 = (float)h1v[u];
                ps0 += a0 * as1[seg * 16 + u];
                pd0 += a0 * ad1[seg * 16 + u];
                ps1 += a1 * as1[seg * 16 + 8 + u];
                pd1 += a1 * ad1[seg * 16 + 8 + u];
            }
            als[grow * NH + seg * 2]     = ps0;
            als[grow * NH + seg * 2 + 1] = ps1;
            ald[grow * NH + seg * 2]     = pd0;
            ald[grow * NH + seg * 2 + 1] = pd1;
        }
    }
}

// ======== deterministic 2-pass counting sort (no global atomics) =========
__global__ __launch_bounds__(256) void k_rsA(const int* __restrict__ H,
                                             int* __restrict__ basek,
                                             int* __restrict__ btot) {
    __shared__ int sc[CH];
    int b = blockIdx.x, t = threadIdx.x;
    int v = H[t * NCB + b];
    sc[t] = v;
    __syncthreads();
    for (int s = 1; s < CH; s <<= 1) {
        int u = (t >= s) ? sc[t - s] : 0;
        __syncthreads();
        sc[t] += u;
        __syncthreads();
    }
    basek[b * CH + t] = sc[t] - v;
    if (t == CH - 1) btot[b] = sc[t];
}

// rscatter: computes bbase locally (scan of btot), then scatters packed edges
__global__ __launch_bounds__(256) void k_rscatter(const int* __restrict__ ei,
                                                  const int* __restrict__ basek,
                                                  const int* __restrict__ btot,
                                                  int* __restrict__ stage) {
    __shared__ int sc[256];
    __shared__ int lcur[NCB];
    int k = blockIdx.x, t = threadIdx.x;
    int v = (t < NCB) ? btot[t] : 0;
    sc[t] = v;
    __syncthreads();
    for (int s = 1; s < 256; s <<= 1) {
        int u = (t >= s) ? sc[t - s] : 0;
        __syncthreads();
        sc[t] += u;
        __syncthreads();
    }
    if (t < NCB) lcur[t] = (sc[t] - v) + basek[t * CH + k];
    __syncthreads();
    int e0 = k * EPC, e1 = min(e0 + EPC, NTOT);
    for (int e = e0 + t; e < e1; e += 256) {
        int s, d;
        if (e < NE) { s = ei[e]; d = ei[NE + e]; }
        else        { s = e - NE; d = s; }
        int pos = atomicAdd(&lcur[d >> 8], 1);
        stage[pos] = (s << 8) | (d & 255);
    }
}

// fsort: computes bbase locally, per-bucket hist+scan -> offs, scatter -> ssrc
__global__ __launch_bounds__(256) void k_fsort(const int* __restrict__ stage,
                                               const int* __restrict__ btot,
                                               int* __restrict__ offs,
                                               int* __restrict__ ssrc) {
    __shared__ int sc[256];
    __shared__ int lc[256];
    __shared__ int ls[256];
    __shared__ int lcur[256];
    __shared__ int bb[2];
    int b = blockIdx.x, t = threadIdx.x;
    int v = (t < NCB) ? btot[t] : 0;
    sc[t] = v;
    __syncthreads();
    for (int s = 1; s < 256; s <<= 1) {
        int u = (t >= s) ? sc[t - s] : 0;
        __syncthreads();
        sc[t] += u;
        __syncthreads();
    }
    if (t == b) bb[0] = sc[t] - v;          // bbase[b]
    if (t == b) bb[1] = sc[t];              // bbase[b+1] (inclusive at b)
    if (b == 0 && t == 0) offs[NN] = NTOT;
    lc[t] = 0;
    __syncthreads();
    int base = bb[0];
    int n = bb[1] - base;
    const int* sp = &stage[base];
    for (int i = t; i < n; i += 256) atomicAdd(&lc[sp[i] & 255], 1);
    __syncthreads();
    int hv = lc[t];
    ls[t] = hv;
    __syncthreads();
    for (int s = 1; s < 256; s <<= 1) {
        int u = (t >= s) ? ls[t - s] : 0;
        __syncthreads();
        ls[t] += u;
        __syncthreads();
    }
    int excl = ls[t] - hv;
    int d = b * 256 + t;
    if (d < NN) offs[d] = base + excl;
    lcur[t] = base + excl;
    __syncthreads();
    for (int i = t; i < n; i += 256) {
        int u = sp[i];
        int pos = atomicAdd(&lcur[u & 255], 1);
        ssrc[pos] = u >> 8;
    }
}

// ------- K2: layer-1 aggregation, shuffle-free lane mapping ---------------
// wave per dst. lane l: slot = l>>3 (8 edge slots), hd = l&7 (head).
// Lane computes its OWN weight and gathers its OWN head's half8 — no shfl
// in the loop. Slot-reduce (xor 8/16/32) once per dst at the end.
__global__ __launch_bounds__(256) void k_agg1(const int* __restrict__ offs,
                                              const int* __restrict__ src,
                                              const _Float16* __restrict__ h1h,
                                              const float* __restrict__ als,
                                              const float* __restrict__ ald,
                                              const float* __restrict__ b1,
                                              _Float16* __restrict__ g1h) {
    int d = blockIdx.x * 4 + (threadIdx.x >> 6);
    if (d >= NN) return;
    const int l = threadIdx.x & 63;
    const int slot = l >> 3, hd = l & 7;
    const unsigned hoff = (unsigned)hd * 4u;    // byte offset in als row (32 B)
    const unsigned coff = (unsigned)hd * 16u;   // byte offset in h1h row (128 B)
    const char* alb = (const char*)als;
    const char* h1b = (const char*)h1h;
    int beg = offs[d], end = offs[d + 1];
    float aldv = ald[d * NH + hd];
    float acc[8] = {};
    float wsum = 0.f;

    for (int r = beg; r < end; r += 16) {
        int e0 = r + slot, e1 = e0 + 8;
        bool v0 = e0 < end, v1 = e1 < end;
        int s0 = src[v0 ? e0 : end - 1];
        int s1 = src[v1 ? e1 : end - 1];
        half8 h0 = *(const half8*)(h1b + ((unsigned)s0 * 128u + coff));
        half8 h1v = *(const half8*)(h1b + ((unsigned)s1 * 128u + coff));
        float lg0 = *(const float*)(alb + ((unsigned)s0 * 32u + hoff)) + aldv;
        float lg1 = *(const float*)(alb + ((unsigned)s1 * 32u + hoff)) + aldv;
        lg0 = lg0 > 0.f ? lg0 : 0.2f * lg0;
        lg1 = lg1 > 0.f ? lg1 : 0.2f * lg1;
        float w0 = v0 ? __expf(lg0) : 0.f;
        float w1 = v1 ? __expf(lg1) : 0.f;
        wsum += w0 + w1;
        #pragma unroll
        for (int u = 0; u < 8; ++u)
            acc[u] += w0 * (float)h0[u] + w1 * (float)h1v[u];
    }
    #pragma unroll
    for (int u = 0; u < 8; ++u) {
        acc[u] += __shfl_xor(acc[u], 8);
        acc[u] += __shfl_xor(acc[u], 16);
        acc[u] += __shfl_xor(acc[u], 32);
    }
    wsum += __shfl_xor(wsum, 8);
    wsum += __shfl_xor(wsum, 16);
    wsum += __shfl_xor(wsum, 32);
    if (slot == 0) {
        half8 gv;
        #pragma unroll
        for (int u = 0; u < 8; ++u) {
            float o = acc[u] / wsum + b1[hd * 8 + u];
            o = o > 0.f ? o : (__expf(o) - 1.f);
            gv[u] = (_Float16)o;
        }
        *(half8*)(&g1h[(size_t)d * C1 + hd * 8]) = gv;
    }
}

// ---------------- K3: GEMM2 (64->16, fp16 in) + layer-2 logits ----------------
__global__ __launch_bounds__(256) void k_gemm2(const _Float16* __restrict__ g1h,
                                               const float* __restrict__ W2,
                                               const float* __restrict__ as2,
                                               const float* __restrict__ ad2,
                                               _Float16* __restrict__ h2h,
                                               float* __restrict__ als2,
                                               float* __restrict__ ald2) {
    __shared__ float w2s[C1][17];
    __shared__ _Float16 hact[16][C1 + 8];
    int tid = threadIdx.x;
    for (int i = tid; i < C1 * NC; i += 256) w2s[i >> 4][i & 15] = W2[i];
    int ln = tid >> 4, j = tid & 15;
    int n = blockIdx.x * 16 + ln;
    if (n < NN)
        *(half4*)(&hact[ln][j * 4]) = *(const half4*)(&g1h[(size_t)n * C1 + j * 4]);
    __syncthreads();
    if (n >= NN) return;
    float sum = 0.f;
    #pragma unroll
    for (int c = 0; c < C1; ++c) sum += (float)hact[ln][c] * w2s[c][j];
    h2h[(size_t)n * NC + j] = (_Float16)sum;
    float ps = sum * as2[j], pd = sum * ad2[j];
    #pragma unroll
    for (int w = 1; w < 16; w <<= 1) {
        ps += __shfl_xor(ps, w);
        pd += __shfl_xor(pd, w);
    }
    if (j == 0) { als2[n] = ps; ald2[n] = pd; }
}

// ------- K4: layer-2 aggregation, shuffle-free, fused log_softmax ---------
// wave per dst. lane l: slot = l>>2 (16 edge slots), cq = l&3 (channel quad).
// Weight computed redundantly in the 4 cq lanes of each slot (no shfl).
__global__ __launch_bounds__(256) void k_agg2(const int* __restrict__ offs,
                                              const int* __restrict__ src,
                                              const _Float16* __restrict__ h2h,
                                              const float* __restrict__ als2,
                                              const float* __restrict__ ald2,
                                              const float* __restrict__ b2,
                                              float* __restrict__ out) {
    int d = blockIdx.x * 4 + (threadIdx.x >> 6);
    if (d >= NN) return;
    const int l = threadIdx.x & 63;
    const int slot = l >> 2, cq = l & 3;
    const unsigned coff = (unsigned)cq * 8u;
    const char* h2b = (const char*)h2h;
    const char* alb = (const char*)als2;
    int beg = offs[d], end = offs[d + 1];
    float aldv = ald2[d];
    float acc[4] = {};
    float wsum = 0.f;
    for (int r = beg; r < end; r += 16) {
        int e = r + slot;
        bool v = e < end;
        int s = src[v ? e : end - 1];
        half4 hv = *(const half4*)(h2b + ((unsigned)s * 32u + coff));
        float lg = *(const float*)(alb + (unsigned)s * 4u) + aldv;
        lg = lg > 0.f ? lg : 0.2f * lg;
        float w = v ? __expf(lg) : 0.f;
        wsum += w;
        #pragma unroll
        for (int u = 0; u < 4; ++u)
            acc[u] += w * (float)hv[u];
    }
    // reduce across slots (bits 2..5)
    #pragma unroll
    for (int u = 0; u < 4; ++u) {
        acc[u] += __shfl_xor(acc[u], 4);
        acc[u] += __shfl_xor(acc[u], 8);
        acc[u] += __shfl_xor(acc[u], 16);
        acc[u] += __shfl_xor(acc[u], 32);
    }
    wsum += __shfl_xor(wsum, 4);
    wsum += __shfl_xor(wsum, 8);
    wsum += __shfl_xor(wsum, 16);
    wsum += __shfl_xor(wsum, 32);
    // per-lane: 4 class values; log_softmax across cq lanes (bits 0..1)
    float o[4];
    float m = -1e30f;
    #pragma unroll
    for (int u = 0; u < 4; ++u) {
        o[u] = acc[u] / wsum + b2[cq * 4 + u];
        m = fmaxf(m, o[u]);
    }
    m = fmaxf(m, __shfl_xor(m, 1));
    m = fmaxf(m, __shfl_xor(m, 2));
    float sm = 0.f;
    #pragma unroll
    for (int u = 0; u < 4; ++u) sm += __expf(o[u] - m);
    sm += __shfl_xor(sm, 1);
    sm += __shfl_xor(sm, 2);
    float lse = m + __logf(sm);
    if (slot == 0) {
        float4 ov = make_float4(o[0] - lse, o[1] - lse, o[2] - lse, o[3] - lse);
        *(float4*)(&out[(size_t)d * NC + cq * 4]) = ov;
    }
}

extern "C" void kernel_launch(void* const* d_in, const int* in_sizes, int n_in,
                              void* d_out, int out_size, void* d_ws, size_t ws_size,
                              hipStream_t stream) {
    const float* x   = (const float*)d_in[0];
    const int*   ei  = (const int*)  d_in[1];
    const float* W1  = (const float*)d_in[2];
    const float* as1 = (const float*)d_in[3];
    const float* ad1 = (const float*)d_in[4];
    const float* b1  = (const float*)d_in[5];
    const float* W2  = (const float*)d_in[6];
    const float* as2 = (const float*)d_in[7];
    const float* ad2 = (const float*)d_in[8];
    const float* b2  = (const float*)d_in[9];
    float* ws  = (float*)d_ws;
    float* out = (float*)d_out;

    _Float16*  h1h  = (_Float16*)(ws + OFF_H1H);
    _Float16*  g1h  = (_Float16*)(ws + OFF_G1H);
    _Float16*  h2h  = (_Float16*)(ws + OFF_H2H);
    float* als1 = ws + OFF_ALS1;
    float* ald1 = ws + OFF_ALD1;
    float* als2 = ws + OFF_ALS2;
    float* ald2 = ws + OFF_ALD2;
    int* H      = (int*)(ws + OFF_HM);
    int* basek  = (int*)(ws + OFF_BASEK);
    int* btot   = (int*)(ws + OFF_BTOT);
    int* offs   = (int*)(ws + OFF_OFFS);
    int* ssrc   = (int*)(ws + OFF_SRC);
    int* stage  = (int*)(ws + OFF_STAGE);

    k_g1rh    <<<GB1 + CH,       256, 0, stream>>>(x, W1, as1, ad1, h1h, als1, ald1, ei, H);
    k_rsA     <<<NCB,            256, 0, stream>>>(H, basek, btot);
    k_rscatter<<<CH,             256, 0, stream>>>(ei, basek, btot, stage);
    k_fsort   <<<NCB,            256, 0, stream>>>(stage, btot, offs, ssrc);
    k_agg1    <<<(NN + 3) / 4,   256, 0, stream>>>(offs, ssrc, h1h, als1, ald1, b1, g1h);
    k_gemm2   <<<(NN + 15) / 16, 256, 0, stream>>>(g1h, W2, as2, ad2, h2h, als2, ald2);
    k_agg2    <<<(NN + 3) / 4,   256, 0, stream>>>(offs, ssrc, h2h, als2, ald2, b2, out);
}

// Round 15
// 133.802 us; speedup vs baseline: 1.0936x; 1.0160x over previous
//
#include <hip/hip_runtime.h>
#include <hip/hip_fp16.h>
#include <hip/hip_fp8.h>

#define NN   50000
#define FIN  256
#define C1   64        // HEADS*HID
#define NH   8
#define NC   16
#define NE   1600000
#define NTOT (NE + NN)

#define CH   256                        // pass-1 chunks
#define EPC  ((NTOT + CH - 1) / CH)     // 6446 edges per chunk
#define NCB  196                        // coarse buckets: dst>>8 (256 dsts each)
#define GB1  ((NN + 63) / 64)           // 782 gemm1 blocks

typedef _Float16 half8 __attribute__((ext_vector_type(8)));
typedef _Float16 half4 __attribute__((ext_vector_type(4)));
typedef float f32x4 __attribute__((ext_vector_type(4)));
typedef float floatx2 __attribute__((ext_vector_type(2)));

#if __has_builtin(__builtin_amdgcn_cvt_pk_f32_fp8) && __has_builtin(__builtin_amdgcn_cvt_pk_fp8_f32)
#define FP8_FAST 1
#endif

__device__ __forceinline__ unsigned pack4_fp8(float f0, float f1, float f2, float f3) {
#ifdef FP8_FAST
    int d = 0;
    d = __builtin_amdgcn_cvt_pk_fp8_f32(f0, f1, d, false);
    d = __builtin_amdgcn_cvt_pk_fp8_f32(f2, f3, d, true);
    return (unsigned)d;
#else
    __hip_fp8_e4m3 q0(f0), q1(f1), q2(f2), q3(f3);
    return (unsigned)q0.__x | ((unsigned)q1.__x << 8) |
           ((unsigned)q2.__x << 16) | ((unsigned)q3.__x << 24);
#endif
}

__device__ __forceinline__ void cvt8_fp8(unsigned lo, unsigned hi, float* f) {
#ifdef FP8_FAST
    floatx2 a = __builtin_amdgcn_cvt_pk_f32_fp8((int)lo, false);
    floatx2 b = __builtin_amdgcn_cvt_pk_f32_fp8((int)lo, true);
    floatx2 c = __builtin_amdgcn_cvt_pk_f32_fp8((int)hi, false);
    floatx2 d = __builtin_amdgcn_cvt_pk_f32_fp8((int)hi, true);
    f[0]=a[0]; f[1]=a[1]; f[2]=b[0]; f[3]=b[1];
    f[4]=c[0]; f[5]=c[1]; f[6]=d[0]; f[7]=d[1];
#else
    #pragma unroll
    for (int u = 0; u < 4; ++u) {
        __hip_fp8_e4m3 q; q.__x = (unsigned char)((lo >> (8*u)) & 0xff);
        f[u] = (float)q;
        __hip_fp8_e4m3 p; p.__x = (unsigned char)((hi >> (8*u)) & 0xff);
        f[4+u] = (float)p;
    }
#endif
}

// ---- workspace layout (float-indexed), ~36 MB (d_ws is 256 MiB) ----
// h1f8 [0,0.8M) fp8 (g1rh->agg1) | g1h [1.6M,3.2M) fp16 (agg1->gemm2)
// stage [3.2M,4.85M) sort only; after fsort reused: h2h [3.2M,3.6M),
//   als2 [3.6M,3.65M), ald2 [3.65M,3.7M)
// als1 [6.4M,6.8M) ald1 [6.8M,7.2M) | sort metadata >= 7.2M
#define OFF_H1F8  0
#define OFF_G1H   1600000
#define OFF_STAGE 3200000
#define OFF_H2H   3200000
#define OFF_ALS2  3600000
#define OFF_ALD2  3650000
#define OFF_ALS1  6400000
#define OFF_ALD1  6800000
#define OFF_HM    7200000    // int H[CH*NCB]
#define OFF_BASEK 7300352    // int basek[NCB*CH]
#define OFF_BTOT  7400704    // int btot[NCB]
#define OFF_OFFS  7401600    // int offs[NN+1]
#define OFF_SRC   7451700    // int ssrc[NTOT]
// end = 9,101,700 floats = 36.4 MB

// ------- K1: [blocks 0..781] h1=x@W1 MFMA, A direct-to-register; h1 -> fp8
//         [blocks 782..1037] rh: per-chunk coarse histogram
__global__ __launch_bounds__(256) void k_g1rh(const float* __restrict__ x,
                                              const float* __restrict__ W1,
                                              const float* __restrict__ as1,
                                              const float* __restrict__ ad1,
                                              unsigned char* __restrict__ h1f8,
                                              float* __restrict__ als,
                                              float* __restrict__ ald,
                                              const int* __restrict__ ei,
                                              int* __restrict__ H) {
    __shared__ _Float16 wsT[64][264];   // [col][k] 33.8 KB; reused as hstore
    __shared__ int lh[NCB];
    const int tid = threadIdx.x;

    if (blockIdx.x >= GB1) {            // ---- rh branch ----
        int k = blockIdx.x - GB1;
        for (int i = tid; i < NCB; i += 256) lh[i] = 0;
        __syncthreads();
        int e0 = k * EPC, e1 = min(e0 + EPC, NTOT);
        for (int e = e0 + tid; e < e1; e += 256) {
            int d = (e < NE) ? ei[NE + e] : (e - NE);
            atomicAdd(&lh[d >> 8], 1);
        }
        __syncthreads();
        for (int i = tid; i < NCB; i += 256) H[k * NCB + i] = lh[i];
        return;
    }

    // ---- gemm1 branch ----
    const int r0 = blockIdx.x * 64;
    {   // stage W1 -> wsT[col][k], coalesced f32 reads, half8 writes
        int c = tid & 63, kb = tid >> 6;
        #pragma unroll
        for (int j = 0; j < 8; ++j) {
            int k8 = kb + 4 * j;
            half8 hv;
            #pragma unroll
            for (int u = 0; u < 8; ++u)
                hv[u] = (_Float16)W1[(size_t)(k8 * 8 + u) * C1 + c];
            *(half8*)(&wsT[c][k8 * 8]) = hv;
        }
    }
    __syncthreads();

    const int lane = tid & 63;
    const int wv   = tid >> 6;
    const int colb = lane & 15;
    const int rgrp = lane >> 4;
    const int arow = r0 + wv * 16 + colb;
    const bool arv = arow < NN;
    f32x4 acc[4] = {};
    #pragma unroll
    for (int s = 0; s < 8; ++s) {
        float4 v0 = make_float4(0.f,0.f,0.f,0.f), v1 = v0;
        if (arv) {
            const float4* xp = (const float4*)(&x[(size_t)arow * FIN + s * 32 + rgrp * 8]);
            v0 = xp[0]; v1 = xp[1];
        }
        half8 a;
        a[0]=(_Float16)v0.x; a[1]=(_Float16)v0.y; a[2]=(_Float16)v0.z; a[3]=(_Float16)v0.w;
        a[4]=(_Float16)v1.x; a[5]=(_Float16)v1.y; a[6]=(_Float16)v1.z; a[7]=(_Float16)v1.w;
        #pragma unroll
        for (int ct = 0; ct < 4; ++ct) {
            half8 b = *(half8*)(&wsT[ct * 16 + colb][s * 32 + rgrp * 8]);
            acc[ct] = __builtin_amdgcn_mfma_f32_16x16x32_f16(a, b, acc[ct], 0, 0, 0);
        }
    }
    __syncthreads();                    // wsT reads done; reuse as hstore
    _Float16 (*hstore)[72] = (_Float16(*)[72])wsT;
    #pragma unroll
    for (int j = 0; j < 4; ++j) {
        int row = wv * 16 + rgrp * 4 + j;
        #pragma unroll
        for (int ct = 0; ct < 4; ++ct)
            hstore[row][ct * 16 + colb] = (_Float16)acc[ct][j];
    }
    __syncthreads();
    {   // coalesced fp8 h1 store + lane-local als/ald (2 heads per lane)
        int row = tid >> 2, seg = tid & 3;
        int grow = r0 + row;
        if (grow < NN) {
            half8 h0 = *(half8*)(&hstore[row][seg * 16]);
            half8 h1v = *(half8*)(&hstore[row][seg * 16 + 8]);
            float fv[16];
            #pragma unroll
            for (int u = 0; u < 8; ++u) { fv[u] = (float)h0[u]; fv[8 + u] = (float)h1v[u]; }
            uint4 pk;
            pk.x = pack4_fp8(fv[0],  fv[1],  fv[2],  fv[3]);
            pk.y = pack4_fp8(fv[4],  fv[5],  fv[6],  fv[7]);
            pk.z = pack4_fp8(fv[8],  fv[9],  fv[10], fv[11]);
            pk.w = pack4_fp8(fv[12], fv[13], fv[14], fv[15]);
            *(uint4*)(&h1f8[(size_t)grow * 64 + seg * 16]) = pk;
            float ps0 = 0.f, pd0 = 0.f, ps1 = 0.f, pd1 = 0.f;
            #pragma unroll
            for (int u = 0; u < 8; ++u) {
                ps0 += fv[u]     * as1[seg * 16 + u];
                pd0 += fv[u]     * ad1[seg * 16 + u];
                ps1 += fv[8 + u] * as1[seg * 16 + 8 + u];
                pd1 += fv[8 + u] * ad1[seg * 16 + 8 + u];
            }
            als[grow * NH + seg * 2]     = ps0;
            als[grow * NH + seg * 2 + 1] = ps1;
            ald[grow * NH + seg * 2]     = pd0;
            ald[grow * NH + seg * 2 + 1] = pd1;
        }
    }
}

// ======== deterministic 2-pass counting sort (no global atomics) =========
__global__ __launch_bounds__(256) void k_rsA(const int* __restrict__ H,
                                             int* __restrict__ basek,
                                             int* __restrict__ btot) {
    __shared__ int sc[CH];
    int b = blockIdx.x, t = threadIdx.x;
    int v = H[t * NCB + b];
    sc[t] = v;
    __syncthreads();
    for (int s = 1; s < CH; s <<= 1) {
        int u = (t >= s) ? sc[t - s] : 0;
        __syncthreads();
        sc[t] += u;
        __syncthreads();
    }
    basek[b * CH + t] = sc[t] - v;
    if (t == CH - 1) btot[b] = sc[t];
}

__global__ __launch_bounds__(256) void k_rscatter(const int* __restrict__ ei,
                                                  const int* __restrict__ basek,
                                                  const int* __restrict__ btot,
                                                  int* __restrict__ stage) {
    __shared__ int sc[256];
    __shared__ int lcur[NCB];
    int k = blockIdx.x, t = threadIdx.x;
    int v = (t < NCB) ? btot[t] : 0;
    sc[t] = v;
    __syncthreads();
    for (int s = 1; s < 256; s <<= 1) {
        int u = (t >= s) ? sc[t - s] : 0;
        __syncthreads();
        sc[t] += u;
        __syncthreads();
    }
    if (t < NCB) lcur[t] = (sc[t] - v) + basek[t * CH + k];
    __syncthreads();
    int e0 = k * EPC, e1 = min(e0 + EPC, NTOT);
    for (int e = e0 + t; e < e1; e += 256) {
        int s, d;
        if (e < NE) { s = ei[e]; d = ei[NE + e]; }
        else        { s = e - NE; d = s; }
        int pos = atomicAdd(&lcur[d >> 8], 1);
        stage[pos] = (s << 8) | (d & 255);
    }
}

__global__ __launch_bounds__(256) void k_fsort(const int* __restrict__ stage,
                                               const int* __restrict__ btot,
                                               int* __restrict__ offs,
                                               int* __restrict__ ssrc) {
    __shared__ int sc[256];
    __shared__ int lc[256];
    __shared__ int ls[256];
    __shared__ int lcur[256];
    __shared__ int bb[2];
    int b = blockIdx.x, t = threadIdx.x;
    int v = (t < NCB) ? btot[t] : 0;
    sc[t] = v;
    __syncthreads();
    for (int s = 1; s < 256; s <<= 1) {
        int u = (t >= s) ? sc[t - s] : 0;
        __syncthreads();
        sc[t] += u;
        __syncthreads();
    }
    if (t == b) bb[0] = sc[t] - v;
    if (t == b) bb[1] = sc[t];
    if (b == 0 && t == 0) offs[NN] = NTOT;
    lc[t] = 0;
    __syncthreads();
    int base = bb[0];
    int n = bb[1] - base;
    const int* sp = &stage[base];
    for (int i = t; i < n; i += 256) atomicAdd(&lc[sp[i] & 255], 1);
    __syncthreads();
    int hv = lc[t];
    ls[t] = hv;
    __syncthreads();
    for (int s = 1; s < 256; s <<= 1) {
        int u = (t >= s) ? ls[t - s] : 0;
        __syncthreads();
        ls[t] += u;
        __syncthreads();
    }
    int excl = ls[t] - hv;
    int d = b * 256 + t;
    if (d < NN) offs[d] = base + excl;
    lcur[t] = base + excl;
    __syncthreads();
    for (int i = t; i < n; i += 256) {
        int u = sp[i];
        int pos = atomicAdd(&lcur[u & 255], 1);
        ssrc[pos] = u >> 8;
    }
}

// ------- K2: layer-1 aggregation, fp8 gathers (h1 table L2-resident) ------
// wave per dst. lane l: slot = l>>3 (8 edge slots), hd = l&7 (head).
// Lane computes its own weight and gathers its own head's 8 fp8 channels.
__global__ __launch_bounds__(256) void k_agg1(const int* __restrict__ offs,
                                              const int* __restrict__ src,
                                              const unsigned char* __restrict__ h1f8,
                                              const float* __restrict__ als,
                                              const float* __restrict__ ald,
                                              const float* __restrict__ b1,
                                              _Float16* __restrict__ g1h) {
    int d = blockIdx.x * 4 + (threadIdx.x >> 6);
    if (d >= NN) return;
    const int l = threadIdx.x & 63;
    const int slot = l >> 3, hd = l & 7;
    const unsigned hoff = (unsigned)hd * 4u;    // byte offset in als row (32 B)
    const unsigned coff = (unsigned)hd * 8u;    // byte offset in h1f8 row (64 B)
    const char* alb = (const char*)als;
    int beg = offs[d], end = offs[d + 1];
    float aldv = ald[d * NH + hd];
    float acc[8] = {};
    float wsum = 0.f;

    for (int r = beg; r < end; r += 16) {
        int e0 = r + slot, e1 = e0 + 8;
        bool v0 = e0 < end, v1 = e1 < end;
        int s0 = src[v0 ? e0 : end - 1];
        int s1 = src[v1 ? e1 : end - 1];
        uint2 q0 = *(const uint2*)(h1f8 + ((unsigned)s0 * 64u + coff));
        uint2 q1 = *(const uint2*)(h1f8 + ((unsigned)s1 * 64u + coff));
        float lg0 = *(const float*)(alb + ((unsigned)s0 * 32u + hoff)) + aldv;
        float lg1 = *(const float*)(alb + ((unsigned)s1 * 32u + hoff)) + aldv;
        lg0 = lg0 > 0.f ? lg0 : 0.2f * lg0;
        lg1 = lg1 > 0.f ? lg1 : 0.2f * lg1;
        float w0 = v0 ? __expf(lg0) : 0.f;
        float w1 = v1 ? __expf(lg1) : 0.f;
        wsum += w0 + w1;
        float f0[8], f1[8];
        cvt8_fp8(q0.x, q0.y, f0);
        cvt8_fp8(q1.x, q1.y, f1);
        #pragma unroll
        for (int u = 0; u < 8; ++u)
            acc[u] += w0 * f0[u] + w1 * f1[u];
    }
    #pragma unroll
    for (int u = 0; u < 8; ++u) {
        acc[u] += __shfl_xor(acc[u], 8);
        acc[u] += __shfl_xor(acc[u], 16);
        acc[u] += __shfl_xor(acc[u], 32);
    }
    wsum += __shfl_xor(wsum, 8);
    wsum += __shfl_xor(wsum, 16);
    wsum += __shfl_xor(wsum, 32);
    if (slot == 0) {
        half8 gv;
        #pragma unroll
        for (int u = 0; u < 8; ++u) {
            float o = acc[u] / wsum + b1[hd * 8 + u];
            o = o > 0.f ? o : (__expf(o) - 1.f);
            gv[u] = (_Float16)o;
        }
        *(half8*)(&g1h[(size_t)d * C1 + hd * 8]) = gv;
    }
}

// ---------------- K3: GEMM2 (64->16, fp16 in) + layer-2 logits ----------------
__global__ __launch_bounds__(256) void k_gemm2(const _Float16* __restrict__ g1h,
                                               const float* __restrict__ W2,
                                               const float* __restrict__ as2,
                                               const float* __restrict__ ad2,
                                               _Float16* __restrict__ h2h,
                                               float* __restrict__ als2,
                                               float* __restrict__ ald2) {
    __shared__ float w2s[C1][17];
    __shared__ _Float16 hact[16][C1 + 8];
    int tid = threadIdx.x;
    for (int i = tid; i < C1 * NC; i += 256) w2s[i >> 4][i & 15] = W2[i];
    int ln = tid >> 4, j = tid & 15;
    int n = blockIdx.x * 16 + ln;
    if (n < NN)
        *(half4*)(&hact[ln][j * 4]) = *(const half4*)(&g1h[(size_t)n * C1 + j * 4]);
    __syncthreads();
    if (n >= NN) return;
    float sum = 0.f;
    #pragma unroll
    for (int c = 0; c < C1; ++c) sum += (float)hact[ln][c] * w2s[c][j];
    h2h[(size_t)n * NC + j] = (_Float16)sum;
    float ps = sum * as2[j], pd = sum * ad2[j];
    #pragma unroll
    for (int w = 1; w < 16; w <<= 1) {
        ps += __shfl_xor(ps, w);
        pd += __shfl_xor(pd, w);
    }
    if (j == 0) { als2[n] = ps; ald2[n] = pd; }
}

// ------- K4: layer-2 aggregation, shuffle-free, fused log_softmax ---------
__global__ __launch_bounds__(256) void k_agg2(const int* __restrict__ offs,
                                              const int* __restrict__ src,
                                              const _Float16* __restrict__ h2h,
                                              const float* __restrict__ als2,
                                              const float* __restrict__ ald2,
                                              const float* __restrict__ b2,
                                              float* __restrict__ out) {
    int d = blockIdx.x * 4 + (threadIdx.x >> 6);
    if (d >= NN) return;
    const int l = threadIdx.x & 63;
    const int slot = l >> 2, cq = l & 3;
    const unsigned coff = (unsigned)cq * 8u;
    const char* h2b = (const char*)h2h;
    const char* alb = (const char*)als2;
    int beg = offs[d], end = offs[d + 1];
    float aldv = ald2[d];
    float acc[4] = {};
    float wsum = 0.f;
    for (int r = beg; r < end; r += 16) {
        int e = r + slot;
        bool v = e < end;
        int s = src[v ? e : end - 1];
        half4 hv = *(const half4*)(h2b + ((unsigned)s * 32u + coff));
        float lg = *(const float*)(alb + (unsigned)s * 4u) + aldv;
        lg = lg > 0.f ? lg : 0.2f * lg;
        float w = v ? __expf(lg) : 0.f;
        wsum += w;
        #pragma unroll
        for (int u = 0; u < 4; ++u)
            acc[u] += w * (float)hv[u];
    }
    #pragma unroll
    for (int u = 0; u < 4; ++u) {
        acc[u] += __shfl_xor(acc[u], 4);
        acc[u] += __shfl_xor(acc[u], 8);
        acc[u] += __shfl_xor(acc[u], 16);
        acc[u] += __shfl_xor(acc[u], 32);
    }
    wsum += __shfl_xor(wsum, 4);
    wsum += __shfl_xor(wsum, 8);
    wsum += __shfl_xor(wsum, 16);
    wsum += __shfl_xor(wsum, 32);
    float o[4];
    float m = -1e30f;
    #pragma unroll
    for (int u = 0; u < 4; ++u) {
        o[u] = acc[u] / wsum + b2[cq * 4 + u];
        m = fmaxf(m, o[u]);
    }
    m = fmaxf(m, __shfl_xor(m, 1));
    m = fmaxf(m, __shfl_xor(m, 2));
    float sm = 0.f;
    #pragma unroll
    for (int u = 0; u < 4; ++u) sm += __expf(o[u] - m);
    sm += __shfl_xor(sm, 1);
    sm += __shfl_xor(sm, 2);
    float lse = m + __logf(sm);
    if (slot == 0) {
        float4 ov = make_float4(o[0] - lse, o[1] - lse, o[2] - lse, o[3] - lse);
        *(float4*)(&out[(size_t)d * NC + cq * 4]) = ov;
    }
}

extern "C" void kernel_launch(void* const* d_in, const int* in_sizes, int n_in,
                              void* d_out, int out_size, void* d_ws, size_t ws_size,
                              hipStream_t stream) {
    const float* x   = (const float*)d_in[0];
    const int*   ei  = (const int*)  d_in[1];
    const float* W1  = (const float*)d_in[2];
    const float* as1 = (const float*)d_in[3];
    const float* ad1 = (const float*)d_in[4];
    const float* b1  = (const float*)d_in[5];
    const float* W2  = (const float*)d_in[6];
    const float* as2 = (const float*)d_in[7];
    const float* ad2 = (const float*)d_in[8];
    const float* b2  = (const float*)d_in[9];
    float* ws  = (float*)d_ws;
    float* out = (float*)d_out;

    unsigned char* h1f8 = (unsigned char*)(ws + OFF_H1F8);
    _Float16*  g1h  = (_Float16*)(ws + OFF_G1H);
    _Float16*  h2h  = (_Float16*)(ws + OFF_H2H);
    float* als1 = ws + OFF_ALS1;
    float* ald1 = ws + OFF_ALD1;
    float* als2 = ws + OFF_ALS2;
    float* ald2 = ws + OFF_ALD2;
    int* H      = (int*)(ws + OFF_HM);
    int* basek  = (int*)(ws + OFF_BASEK);
    int* btot   = (int*)(ws + OFF_BTOT);
    int* offs   = (int*)(ws + OFF_OFFS);
    int* ssrc   = (int*)(ws + OFF_SRC);
    int* stage  = (int*)(ws + OFF_STAGE);

    k_g1rh    <<<GB1 + CH,       256, 0, stream>>>(x, W1, as1, ad1, h1f8, als1, ald1, ei, H);
    k_rsA     <<<NCB,            256, 0, stream>>>(H, basek, btot);
    k_rscatter<<<CH,             256, 0, stream>>>(ei, basek, btot, stage);
    k_fsort   <<<NCB,            256, 0, stream>>>(stage, btot, offs, ssrc);
    k_agg1    <<<(NN + 3) / 4,   256, 0, stream>>>(offs, ssrc, h1f8, als1, ald1, b1, g1h);
    k_gemm2   <<<(NN + 15) / 16, 256, 0, stream>>>(g1h, W2, as2, ad2, h2h, als2, ald2);
    k_agg2    <<<(NN + 3) / 4,   256, 0, stream>>>(offs, ssrc, h2h, als2, ald2, b2, out);
}